// Round 7
// baseline (9555.434 us; speedup 1.0000x reference)
//
#include <hip/hip_runtime.h>

#define BATCH  200
#define IN_DIM 2312
#define HD1    800
#define HD2    10
#define TWIN   8

#define MPAD   256
#define KPAD   2336
#define NPAD   896
#define JPAD   832
#define BPAD   224
#define N2PAD  2432
#define NS1    8
#define NBLK   256

#define PLA    ((size_t)MPAD * KPAD)    // 598016
#define PLB    ((size_t)N2PAD * BPAD)   // 544768
#define NK     ((size_t)NPAD * KPAD)    // 2093056
#define JB     ((size_t)JPAD * BPAD)    // 186368
// single-buffered: 3*(PLA+PLB+NK+JB) = 10,266,624 ushorts -> 1,283,328 uint4
#define ZERO_UINT4 1283328

typedef __attribute__((ext_vector_type(8))) short bf16x8;
typedef __attribute__((ext_vector_type(4))) float f32x4;

__device__ __forceinline__ unsigned short f2bf(float x) {
  unsigned u = __builtin_bit_cast(unsigned, x);
  u = (u + 0x7FFFu + ((u >> 16) & 1u)) >> 16;
  return (unsigned short)u;
}
__device__ __forceinline__ float bf2f(unsigned short h) {
  unsigned u = ((unsigned)h) << 16;
  return __builtin_bit_cast(float, u);
}
__device__ __forceinline__ void split3(float x, unsigned short& h, unsigned short& m,
                                       unsigned short& l) {
  h = f2bf(x);
  float r1 = x - bf2f(h);
  m = f2bf(r1);
  float r2 = r1 - bf2f(m);
  l = f2bf(r2);
}

struct Params {
  const float *input, *hebb1_in, *hebb2_in, *W1, *b1, *W2, *b2;
  const float *alpha1, *alpha2, *beta1, *beta2, *eta1, *eta2;
  float *outs, *hebb1out, *hebb2o;
  unsigned short *XAh, *XAm, *XAl, *XBh, *XBm, *XBl;
  unsigned short *Wch, *Wcm, *Wcl, *PTh, *PTm, *PTl;
  float *part, *H, *mem1, *spike1, *mem2, *spike2, *post2;
  unsigned *bar_cnt, *bar_gen;
};

// ---------------------------------------------------------------------------
// software grid barrier: device-scope atomics + fences (256 blocks on 256 CUs,
// 46KB LDS, launch_bounds(256,1) -> co-residency; verified executing in R6).
// ---------------------------------------------------------------------------
__device__ __forceinline__ void gsync(unsigned* cnt, unsigned* gen) {
  __syncthreads();
  if (threadIdx.x == 0) {
    __threadfence();   // release: prior writes visible device-wide
    unsigned g = __hip_atomic_load(gen, __ATOMIC_RELAXED, __HIP_MEMORY_SCOPE_AGENT);
    unsigned a = __hip_atomic_fetch_add(cnt, 1u, __ATOMIC_ACQ_REL, __HIP_MEMORY_SCOPE_AGENT);
    if (a == NBLK - 1) {
      __hip_atomic_store(cnt, 0u, __ATOMIC_RELAXED, __HIP_MEMORY_SCOPE_AGENT);
      __threadfence();  // order cnt reset before gen bump
      __hip_atomic_fetch_add(gen, 1u, __ATOMIC_RELEASE, __HIP_MEMORY_SCOPE_AGENT);
    } else {
      while (__hip_atomic_load(gen, __ATOMIC_ACQUIRE, __HIP_MEMORY_SCOPE_AGENT) == g)
        __builtin_amdgcn_s_sleep(4);
    }
    __threadfence();   // acquire: subsequent reads see fresh data
  }
  __syncthreads();
}

// 64x64 float tile transpose: src[R][C] -> dst[C][R]
__device__ __forceinline__ void tile_tr(const float* __restrict__ src, int R, int C,
                                        float* __restrict__ dst, int r0, int c0,
                                        float* t /*64*65*/, int tid) {
#pragma unroll
  for (int q = 0; q < 16; q++) {
    int idx = q * 256 + tid;
    int r = idx >> 6, c = idx & 63;
    float v = (r0 + r < R && c0 + c < C) ? src[(size_t)(r0 + r) * C + c0 + c] : 0.f;
    t[r * 65 + c] = v;
  }
  __syncthreads();
#pragma unroll
  for (int q = 0; q < 16; q++) {
    int idx = q * 256 + tid;
    int r = idx >> 6, c = idx & 63;
    if (c0 + r < C && r0 + c < R) dst[(size_t)(c0 + r) * R + r0 + c] = t[c * 65 + r];
  }
  __syncthreads();
}

// split one 32x32 tile of input slice t into XA (h/m/l) and XB (h/m/l)
__device__ __forceinline__ void split_x_tile(const float* __restrict__ in, int t, int job,
                                             unsigned short* XAh, unsigned short* XAm,
                                             unsigned short* XAl, unsigned short* XBh,
                                             unsigned short* XBm, unsigned short* XBl,
                                             unsigned short* sm /*3*1056*/, int tid) {
  int it = job % 73, bt = job / 73;
  int i0 = it * 32, b0 = bt * 32;
  int il = tid & 31, q0 = tid >> 5;
#pragma unroll
  for (int q = 0; q < 4; q++) {
    int bl = q0 + q * 8;
    int b = b0 + bl, i = i0 + il;
    float v = (b < BATCH && i < IN_DIM) ? in[(((size_t)b * IN_DIM + i) << 3) + t] : 0.f;
    unsigned short vh, vm, vl;
    split3(v, vh, vm, vl);
    size_t ax = (size_t)(b0 + bl) * KPAD + i;
    XAh[ax] = vh; XAm[ax] = vm; XAl[ax] = vl;
    sm[0 * 1056 + bl * 33 + il] = vh;
    sm[1 * 1056 + bl * 33 + il] = vm;
    sm[2 * 1056 + bl * 33 + il] = vl;
  }
  __syncthreads();
#pragma unroll
  for (int q = 0; q < 4; q++) {
    int il2 = q0 + q * 8;
    int bl2 = il;
    size_t bx = (size_t)(i0 + il2) * BPAD + b0 + bl2;
    XBh[bx] = sm[0 * 1056 + bl2 * 33 + il2];
    XBm[bx] = sm[1 * 1056 + bl2 * 33 + il2];
    XBl[bx] = sm[2 * 1056 + bl2 * 33 + il2];
  }
  __syncthreads();
}

// GEMM1 tile job: part[s] = XA(64 rows) x Wc(128 cols), K-chunk s
__device__ __forceinline__ void gemm1_body(
    int job, const unsigned short* __restrict__ XAh, const unsigned short* __restrict__ XAm,
    const unsigned short* __restrict__ XAl, const unsigned short* __restrict__ Wch,
    const unsigned short* __restrict__ Wcm, const unsigned short* __restrict__ Wcl,
    float* __restrict__ part, unsigned short* sm, int tid) {
  unsigned short* Ab = sm;          // [3][64*40]
  unsigned short* Bb = sm + 7680;   // [3][128*40]
  int s = job / 28, rr = job % 28;
  int m0 = (rr / 7) * 64, n0 = (rr % 7) * 128;
  int it0 = s * 9, it1 = (s == NS1 - 1) ? 73 : it0 + 9;
  int r = tid >> 2, g = tid & 3;
  int w = tid >> 6, lane = tid & 63;
  int wm = w >> 1, wn = w & 1, lr = lane & 15, lg = lane >> 4;
  f32x4 acc[2][4] = {};
  for (int it = it0; it < it1; ++it) {
    int k0 = it * 32;
    size_t ga = (size_t)(m0 + r) * KPAD + k0 + g * 8;
    uint4 a0 = *(const uint4*)&XAh[ga];
    uint4 a1 = *(const uint4*)&XAm[ga];
    uint4 a2 = *(const uint4*)&XAl[ga];
    size_t gb0 = (size_t)(n0 + r) * KPAD + k0 + g * 8;
    size_t gb1 = gb0 + (size_t)64 * KPAD;
    uint4 b0 = *(const uint4*)&Wch[gb0];
    uint4 b1 = *(const uint4*)&Wcm[gb0];
    uint4 b2 = *(const uint4*)&Wcl[gb0];
    uint4 b3 = *(const uint4*)&Wch[gb1];
    uint4 b4 = *(const uint4*)&Wcm[gb1];
    uint4 b5 = *(const uint4*)&Wcl[gb1];
    __syncthreads();
    int la = r * 40 + g * 8;
    *(uint4*)&Ab[0 * 2560 + la] = a0; *(uint4*)&Ab[1 * 2560 + la] = a1; *(uint4*)&Ab[2 * 2560 + la] = a2;
    *(uint4*)&Bb[0 * 5120 + la] = b0; *(uint4*)&Bb[1 * 5120 + la] = b1; *(uint4*)&Bb[2 * 5120 + la] = b2;
    int lb = la + 2560;
    *(uint4*)&Bb[0 * 5120 + lb] = b3; *(uint4*)&Bb[1 * 5120 + lb] = b4; *(uint4*)&Bb[2 * 5120 + lb] = b5;
    __syncthreads();
    bf16x8 ah[2], am[2], al[2];
#pragma unroll
    for (int fm = 0; fm < 2; fm++) {
      int row = (wm * 32 + fm * 16 + lr) * 40 + lg * 8;
      ah[fm] = *(const bf16x8*)&Ab[0 * 2560 + row];
      am[fm] = *(const bf16x8*)&Ab[1 * 2560 + row];
      al[fm] = *(const bf16x8*)&Ab[2 * 2560 + row];
    }
#pragma unroll
    for (int fn = 0; fn < 4; fn++) {
      int rown = (wn * 64 + fn * 16 + lr) * 40 + lg * 8;
      bf16x8 bh = *(const bf16x8*)&Bb[0 * 5120 + rown];
      bf16x8 bm = *(const bf16x8*)&Bb[1 * 5120 + rown];
      bf16x8 bl = *(const bf16x8*)&Bb[2 * 5120 + rown];
#pragma unroll
      for (int fm = 0; fm < 2; fm++) {
        f32x4 c = acc[fm][fn];
        c = __builtin_amdgcn_mfma_f32_16x16x32_bf16(ah[fm], bh, c, 0, 0, 0);
        c = __builtin_amdgcn_mfma_f32_16x16x32_bf16(ah[fm], bm, c, 0, 0, 0);
        c = __builtin_amdgcn_mfma_f32_16x16x32_bf16(am[fm], bh, c, 0, 0, 0);
        c = __builtin_amdgcn_mfma_f32_16x16x32_bf16(ah[fm], bl, c, 0, 0, 0);
        c = __builtin_amdgcn_mfma_f32_16x16x32_bf16(al[fm], bh, c, 0, 0, 0);
        c = __builtin_amdgcn_mfma_f32_16x16x32_bf16(am[fm], bm, c, 0, 0, 0);
        acc[fm][fn] = c;
      }
    }
  }
  float* pp = part + (size_t)s * (BATCH * HD1);
#pragma unroll
  for (int fm = 0; fm < 2; fm++)
#pragma unroll
    for (int fn = 0; fn < 4; fn++) {
      int n = n0 + wn * 64 + fn * 16 + lr;
      if (n >= HD1) continue;
      int mb = m0 + wm * 32 + fm * 16 + lg * 4;
#pragma unroll
      for (int r4 = 0; r4 < 4; r4++) {
        int m = mb + r4;
        if (m < BATCH) pp[(size_t)m * HD1 + n] = acc[fm][fn][r4];
      }
    }
}

// GEMM2 tile job + hebb1(H)/Wc-split epilogue
__device__ __forceinline__ void gemm2_body(
    int job, const unsigned short* __restrict__ PTh, const unsigned short* __restrict__ PTm,
    const unsigned short* __restrict__ PTl, const unsigned short* __restrict__ XBh,
    const unsigned short* __restrict__ XBm, const unsigned short* __restrict__ XBl,
    const float* __restrict__ beta1, const float* __restrict__ W1,
    const float* __restrict__ alpha1, float* __restrict__ H,
    unsigned short* __restrict__ Wch, unsigned short* __restrict__ Wcm,
    unsigned short* __restrict__ Wcl, unsigned short* sm, int tid) {
  unsigned short* Ab = sm;
  unsigned short* Bb = sm + 7680;
  int m0 = (job / 19) * 64, n0 = (job % 19) * 128;
  int r = tid >> 2, g = tid & 3;
  int w = tid >> 6, lane = tid & 63;
  int wm = w >> 1, wn = w & 1, lr = lane & 15, lg = lane >> 4;
  f32x4 acc[2][4] = {};
  for (int it = 0; it < 7; ++it) {
    int k0 = it * 32;
    size_t ga = (size_t)(m0 + r) * BPAD + k0 + g * 8;
    uint4 a0 = *(const uint4*)&PTh[ga];
    uint4 a1 = *(const uint4*)&PTm[ga];
    uint4 a2 = *(const uint4*)&PTl[ga];
    size_t gb0 = (size_t)(n0 + r) * BPAD + k0 + g * 8;
    size_t gb1 = gb0 + (size_t)64 * BPAD;
    uint4 b0 = *(const uint4*)&XBh[gb0];
    uint4 b1 = *(const uint4*)&XBm[gb0];
    uint4 b2 = *(const uint4*)&XBl[gb0];
    uint4 b3 = *(const uint4*)&XBh[gb1];
    uint4 b4 = *(const uint4*)&XBm[gb1];
    uint4 b5 = *(const uint4*)&XBl[gb1];
    __syncthreads();
    int la = r * 40 + g * 8;
    *(uint4*)&Ab[0 * 2560 + la] = a0; *(uint4*)&Ab[1 * 2560 + la] = a1; *(uint4*)&Ab[2 * 2560 + la] = a2;
    *(uint4*)&Bb[0 * 5120 + la] = b0; *(uint4*)&Bb[1 * 5120 + la] = b1; *(uint4*)&Bb[2 * 5120 + la] = b2;
    int lb = la + 2560;
    *(uint4*)&Bb[0 * 5120 + lb] = b3; *(uint4*)&Bb[1 * 5120 + lb] = b4; *(uint4*)&Bb[2 * 5120 + lb] = b5;
    __syncthreads();
    bf16x8 ah[2], am[2], al[2];
#pragma unroll
    for (int fm = 0; fm < 2; fm++) {
      int row = (wm * 32 + fm * 16 + lr) * 40 + lg * 8;
      ah[fm] = *(const bf16x8*)&Ab[0 * 2560 + row];
      am[fm] = *(const bf16x8*)&Ab[1 * 2560 + row];
      al[fm] = *(const bf16x8*)&Ab[2 * 2560 + row];
    }
#pragma unroll
    for (int fn = 0; fn < 4; fn++) {
      int rown = (wn * 64 + fn * 16 + lr) * 40 + lg * 8;
      bf16x8 bh = *(const bf16x8*)&Bb[0 * 5120 + rown];
      bf16x8 bm = *(const bf16x8*)&Bb[1 * 5120 + rown];
      bf16x8 bl = *(const bf16x8*)&Bb[2 * 5120 + rown];
#pragma unroll
      for (int fm = 0; fm < 2; fm++) {
        f32x4 c = acc[fm][fn];
        c = __builtin_amdgcn_mfma_f32_16x16x32_bf16(ah[fm], bh, c, 0, 0, 0);
        c = __builtin_amdgcn_mfma_f32_16x16x32_bf16(ah[fm], bm, c, 0, 0, 0);
        c = __builtin_amdgcn_mfma_f32_16x16x32_bf16(am[fm], bh, c, 0, 0, 0);
        c = __builtin_amdgcn_mfma_f32_16x16x32_bf16(ah[fm], bl, c, 0, 0, 0);
        c = __builtin_amdgcn_mfma_f32_16x16x32_bf16(al[fm], bh, c, 0, 0, 0);
        c = __builtin_amdgcn_mfma_f32_16x16x32_bf16(am[fm], bm, c, 0, 0, 0);
        acc[fm][fn] = c;
      }
    }
  }
  float al1 = alpha1[0];
#pragma unroll
  for (int fm = 0; fm < 2; fm++)
#pragma unroll
    for (int fn = 0; fn < 4; fn++) {
      int i = n0 + wn * 64 + fn * 16 + lr;
      if (i >= IN_DIM) continue;
      float bc = fmaxf(beta1[i], 0.f);
      int jb = m0 + wm * 32 + fm * 16 + lg * 4;
#pragma unroll
      for (int r4 = 0; r4 < 4; r4++) {
        int j = jb + r4;
        if (j >= HD1) continue;
        size_t hx = (size_t)j * IN_DIM + i;
        float h = 0.99f * H[hx] - bc * acc[fm][fn][r4] * (1.f / 200.f);
        h = fminf(fmaxf(h, -5.f), 5.f);
        H[hx] = h;
        unsigned short vh, vm, vl;
        split3(W1[hx] + al1 * h, vh, vm, vl);
        size_t wx = (size_t)j * KPAD + i;
        Wch[wx] = vh; Wcm[wx] = vm; Wcl[wx] = vl;
      }
    }
}

// ---------------------------------------------------------------------------
// barrier init (ws is poisoned 0xAA once before timing; re-zero every call)
// ---------------------------------------------------------------------------
__global__ void k_bar_init(unsigned* bar) { bar[0] = 0u; bar[1] = 0u; }

// ---------------------------------------------------------------------------
// the mega-kernel: entire model, one persistent launch + software grid barrier
// phases: A(init) B(Wc split) then per t: P0(x-split) P1(gemm1) P2(reduce+mem)
// P3(layer2) P4(gemm2+hebb)  — x-split in its OWN phase: P4 reads XB(t), so
// XB(t+1) may only be written after P4's barrier (this was R6's race).
// ---------------------------------------------------------------------------
__global__ __launch_bounds__(256, 1) void k_mega(Params p) {
  __shared__ __align__(16) unsigned char smem_raw[46080];
  unsigned short* sm_us = (unsigned short*)smem_raw;
  float* sm_f = (float*)smem_raw;
  unsigned* cnt = p.bar_cnt;
  unsigned* gen = p.bar_gen;
  int tid = threadIdx.x, bid = blockIdx.x;
  int gtid = bid * 256 + tid;
  int gwave = (gtid >> 6);   // 0..1023

  // ============ phase A: zero pads, init states, H = hebb1_in^T ============
  {
    uint4* z = (uint4*)p.XAh;
    for (int k = gtid; k < ZERO_UINT4; k += 65536) z[k] = make_uint4(0, 0, 0, 0);
    for (int k = gtid; k < BATCH * HD1; k += 65536) { p.mem1[k] = 0.f; p.spike1[k] = 0.f; }
    for (int k = gtid; k < HD1 * HD2; k += 65536) p.hebb2o[k] = p.hebb2_in[k];
    if (gtid < BATCH * HD2) { p.mem2[gtid] = 0.f; p.spike2[gtid] = 0.f; p.post2[gtid] = 0.f; }
    for (int job = bid; job < 37 * 13; job += NBLK)
      tile_tr(p.hebb1_in, IN_DIM, HD1, p.H, (job / 13) * 64, (job % 13) * 64, sm_f, tid);
  }
  gsync(cnt, gen);

  // ============ phase B: initial Wc split ============
  {
    float al = p.alpha1[0];
    for (int id = gtid; id < HD1 * (IN_DIM / 8); id += 65536) {
      int j = id / (IN_DIM / 8);
      int i8 = (id % (IN_DIM / 8)) * 8;
      size_t sx = (size_t)j * IN_DIM + i8;
      size_t dx = (size_t)j * KPAD + i8;
#pragma unroll
      for (int q = 0; q < 8; q++) {
        unsigned short vh, vm, vl;
        split3(p.W1[sx + q] + al * p.H[sx + q], vh, vm, vl);
        p.Wch[dx + q] = vh; p.Wcm[dx + q] = vm; p.Wcl[dx + q] = vl;
      }
    }
  }
  gsync(cnt, gen);

  // ============ timestep loop ============
  for (int t = 0; t < TWIN; t++) {
    // ---- P0: x-split(t) into XA/XB (own phase: XB(t-1) reads finished at
    //      P4's barrier; XA/XB(t) must be complete before P1/P4 read) ----
    for (int job = bid; job < 511; job += NBLK)
      split_x_tile(p.input, t, job, p.XAh, p.XAm, p.XAl, p.XBh, p.XBm, p.XBl, sm_us, tid);
    gsync(cnt, gen);

    // ---- P1: GEMM1 (224 jobs) ----
    if (bid < 224)
      gemm1_body(bid, p.XAh, p.XAm, p.XAl, p.Wch, p.Wcm, p.Wcl, p.part, sm_us, tid);
    gsync(cnt, gen);

    // ---- P2: split-K reduce + membrane + PT splits ----
    if (gtid < BATCH * (HD1 / 4)) {
      int m = gtid / (HD1 / 4);
      int n4 = (gtid % (HD1 / 4)) * 4;
      size_t idx = (size_t)m * HD1 + n4;
      float4 sum = *(const float4*)&p.part[idx];
#pragma unroll
      for (int s = 1; s < NS1; s++) {
        float4 q4 = *(const float4*)&p.part[(size_t)s * BATCH * HD1 + idx];
        sum.x += q4.x; sum.y += q4.y; sum.z += q4.z; sum.w += q4.w;
      }
      float4 bb = *(const float4*)&p.b1[n4];
      float4 ee = *(const float4*)&p.eta1[n4];
      float4 mo = *(const float4*)&p.mem1[idx];
      float4 so = *(const float4*)&p.spike1[idx];
      float st[4]  = {sum.x + bb.x, sum.y + bb.y, sum.z + bb.z, sum.w + bb.w};
      float mof[4] = {mo.x, mo.y, mo.z, mo.w};
      float sof[4] = {so.x, so.y, so.z, so.w};
      float eef[4] = {ee.x, ee.y, ee.z, ee.w};
      float mn[4], sp[4];
#pragma unroll
      for (int q = 0; q < 4; q++) {
        mn[q] = mof[q] * (1.f - sof[q]) * 0.25f + st[q];
        sp[q] = (mn[q] - 0.4f > 0.f) ? 1.f : 0.f;
        float po = mn[q] * 2.5f - eef[q];
        unsigned short vh, vm, vl;
        split3(po, vh, vm, vl);
        size_t px = (size_t)(n4 + q) * BPAD + m;
        p.PTh[px] = vh; p.PTm[px] = vm; p.PTl[px] = vl;
      }
      *(float4*)&p.mem1[idx]   = make_float4(mn[0], mn[1], mn[2], mn[3]);
      *(float4*)&p.spike1[idx] = make_float4(sp[0], sp[1], sp[2], sp[3]);
    }
    gsync(cnt, gen);

    // ---- P3: layer-2 state (wave jobs) ----
    {
      float al2 = p.alpha2[0];
      int lane = tid & 63;
      for (int wid = gwave; wid < BATCH * HD2; wid += 1024) {
        int b = wid / HD2, j = wid % HD2;
        float acc = 0.f;
        for (int i = lane; i < HD1; i += 64)
          acc += p.spike1[b * HD1 + i] * (p.W2[j * HD1 + i] + al2 * p.hebb2o[i * HD2 + j]);
#pragma unroll
        for (int off = 32; off > 0; off >>= 1) acc += __shfl_down(acc, off, 64);
        if (lane == 0) {
          float state = acc + p.b2[j];
          int idx = b * HD2 + j;
          float mo = p.mem2[idx], so = p.spike2[idx];
          float mnv = mo * (1.f - so) * 0.25f + state;
          p.mem2[idx]   = mnv;
          p.spike2[idx] = (mnv - 0.4f > 0.f) ? 1.f : 0.f;
          p.post2[idx]  = mnv * 2.5f - p.eta2[j];
          p.outs[idx]   = mnv * 2.5f;
        }
      }
    }
    gsync(cnt, gen);

    // ---- P4: GEMM2 + hebb1/Wc epilogue (247 jobs) || hebb2 (9 blocks) ----
    if (bid < 247) {
      gemm2_body(bid, p.PTh, p.PTm, p.PTl, p.XBh, p.XBm, p.XBl, p.beta1, p.W1,
                 p.alpha1, p.H, p.Wch, p.Wcm, p.Wcl, sm_us, tid);
    } else {
      int lid = (bid - 247) * 256 + tid;
      for (int idx = lid; idx < HD1 * HD2; idx += 2304) {
        int i = idx % HD1, j = idx / HD1;
        float acc = 0.f;
        for (int b = 0; b < BATCH; b++)
          acc += p.spike1[b * HD1 + i] * p.post2[b * HD2 + j];
        float bc = fmaxf(p.beta2[i], 0.f);
        float h = 0.99f * p.hebb2o[i * HD2 + j] - bc * acc * (1.f / 200.f);
        p.hebb2o[i * HD2 + j] = fminf(fmaxf(h, -5.f), 5.f);
      }
    }
    gsync(cnt, gen);
  }

  // ============ final: hebb1out = H^T ============
  for (int job = bid; job < 13 * 37; job += NBLK)
    tile_tr(p.H, HD1, IN_DIM, p.hebb1out, (job / 37) * 64, (job % 37) * 64, sm_f, tid);
}

// ---------------------------------------------------------------------------
extern "C" void kernel_launch(void* const* d_in, const int* in_sizes, int n_in,
                              void* d_out, int out_size, void* d_ws, size_t ws_size,
                              hipStream_t stream) {
  Params p;
  p.input    = (const float*)d_in[0];
  p.hebb1_in = (const float*)d_in[1];
  p.hebb2_in = (const float*)d_in[2];
  p.W1       = (const float*)d_in[3];
  p.b1       = (const float*)d_in[4];
  p.W2       = (const float*)d_in[5];
  p.b2       = (const float*)d_in[6];
  p.alpha1   = (const float*)d_in[7];
  p.alpha2   = (const float*)d_in[8];
  p.beta1    = (const float*)d_in[9];
  p.beta2    = (const float*)d_in[10];
  p.eta1     = (const float*)d_in[11];
  p.eta2     = (const float*)d_in[12];

  float* out = (float*)d_out;
  p.outs     = out;
  p.hebb1out = out + BATCH * HD2;
  p.hebb2o   = p.hebb1out + (size_t)IN_DIM * HD1;

  // ws layout: [0,256) barrier words; then ushort split arrays; then fp arrays
  p.bar_cnt = (unsigned*)d_ws;
  p.bar_gen = p.bar_cnt + 1;
  unsigned short* us = (unsigned short*)((char*)d_ws + 256);
  p.XAh = us;
  p.XAm = p.XAh + PLA;
  p.XAl = p.XAm + PLA;
  p.XBh = p.XAl + PLA;
  p.XBm = p.XBh + PLB;
  p.XBl = p.XBm + PLB;
  p.Wch = p.XBl + PLB;
  p.Wcm = p.Wch + NK;
  p.Wcl = p.Wcm + NK;
  p.PTh = p.Wcl + NK;
  p.PTm = p.PTh + JB;
  p.PTl = p.PTm + JB;
  size_t us_total = 3 * (PLA + PLB + NK + JB);   // 10,266,624

  float* fp = (float*)(us + us_total);
  p.part   = fp;
  p.H      = p.part + (size_t)NS1 * BATCH * HD1;
  p.mem1   = p.H + (size_t)HD1 * IN_DIM;
  p.spike1 = p.mem1 + BATCH * HD1;
  p.mem2   = p.spike1 + BATCH * HD1;
  p.spike2 = p.mem2 + BATCH * HD2;
  p.post2  = p.spike2 + BATCH * HD2;

  k_bar_init<<<1, 1, 0, stream>>>(p.bar_cnt);
  k_mega<<<NBLK, 256, 0, stream>>>(p);
}

// Round 8
// 7965.977 us; speedup vs baseline: 1.1995x; 1.1995x over previous
//
#include <hip/hip_runtime.h>

#define BATCH  200
#define IN_DIM 2312
#define HD1    800
#define HD2    10
#define TWIN   8

#define MPAD   256
#define KPAD   2336
#define NPAD   896
#define JPAD   832
#define BPAD   224
#define N2PAD  2432
#define NS1    8
#define NBLK   256

#define PLA    ((size_t)MPAD * KPAD)    // 598016
#define PLB    ((size_t)N2PAD * BPAD)   // 544768
#define NK     ((size_t)NPAD * KPAD)    // 2093056
#define JB     ((size_t)JPAD * BPAD)    // 186368
#define ZERO_UINT4 1283328              // 3*(PLA+PLB+NK+JB)/8

#define FLAG_STRIDE 32                  // 32 uints = 128B per flag line
#define BAR_BYTES   36864               // flags (32KB) + gen, padded
#define WS_BASE     (36864 + 20533248 + 13822400)   // = 34,392,512
#define WS_NEEDED   (WS_BASE + 14796800)            // + xall fp32

typedef __attribute__((ext_vector_type(8))) short bf16x8;
typedef __attribute__((ext_vector_type(4))) float f32x4;

__device__ __forceinline__ unsigned short f2bf(float x) {
  unsigned u = __builtin_bit_cast(unsigned, x);
  u = (u + 0x7FFFu + ((u >> 16) & 1u)) >> 16;
  return (unsigned short)u;
}
__device__ __forceinline__ float bf2f(unsigned short h) {
  unsigned u = ((unsigned)h) << 16;
  return __builtin_bit_cast(float, u);
}
__device__ __forceinline__ void split3(float x, unsigned short& h, unsigned short& m,
                                       unsigned short& l) {
  h = f2bf(x);
  float r1 = x - bf2f(h);
  m = f2bf(r1);
  float r2 = r1 - bf2f(m);
  l = f2bf(r2);
}

struct Params {
  const float *input, *hebb1_in, *hebb2_in, *W1, *b1, *W2, *b2;
  const float *alpha1, *alpha2, *beta1, *beta2, *eta1, *eta2;
  float *outs, *hebb1out, *hebb2o;
  unsigned short *XAh, *XAm, *XAl, *XBh, *XBm, *XBl;
  unsigned short *Wch, *Wcm, *Wcl, *PTh, *PTm, *PTl;
  float *part, *H, *mem1, *spike1, *mem2, *spike2, *post2;
  float *xall;              // [T][B][IN_DIM] or nullptr (ws too small)
  unsigned *flags, *gen;    // barrier state
};

// ---------------------------------------------------------------------------
// flag-array grid barrier: per-block padded arrival flags (parallel stores,
// no RMW contention) + block-0 wave-0 poll + single gen broadcast.
// R7's single-counter version cost ~227us/barrier (256 serialized cross-XCD
// RMWs on one line, MfmaUtil 0.4%); this replaces it with 2 propagation hops.
// ---------------------------------------------------------------------------
__device__ __forceinline__ void gsync(unsigned* flags, unsigned* gen, unsigned bar_no) {
  __syncthreads();
  int tid = threadIdx.x;
  if (blockIdx.x == 0) {
    if (tid < 64) {
      for (;;) {
        bool ok = true;
#pragma unroll
        for (int q = 0; q < 4; q++) {
          int b = tid * 4 + q;
          if (b != 0) {
            unsigned v = __hip_atomic_load(&flags[b * FLAG_STRIDE], __ATOMIC_ACQUIRE,
                                           __HIP_MEMORY_SCOPE_AGENT);
            if (v < bar_no) ok = false;
          }
        }
        if (__all(ok)) break;
        __builtin_amdgcn_s_sleep(2);
      }
    }
    __syncthreads();
    if (tid == 0) {
      __threadfence();
      __hip_atomic_store(gen, bar_no, __ATOMIC_RELEASE, __HIP_MEMORY_SCOPE_AGENT);
    }
  } else {
    if (tid == 0) {
      __threadfence();
      __hip_atomic_store(&flags[blockIdx.x * FLAG_STRIDE], bar_no, __ATOMIC_RELEASE,
                         __HIP_MEMORY_SCOPE_AGENT);
      while (__hip_atomic_load(gen, __ATOMIC_ACQUIRE, __HIP_MEMORY_SCOPE_AGENT) < bar_no)
        __builtin_amdgcn_s_sleep(8);
      __threadfence();
    }
  }
  __syncthreads();
}

// 64x64 float tile transpose: src[R][C] -> dst[C][R]
__device__ __forceinline__ void tile_tr(const float* __restrict__ src, int R, int C,
                                        float* __restrict__ dst, int r0, int c0,
                                        float* t /*64*65*/, int tid) {
#pragma unroll
  for (int q = 0; q < 16; q++) {
    int idx = q * 256 + tid;
    int r = idx >> 6, c = idx & 63;
    float v = (r0 + r < R && c0 + c < C) ? src[(size_t)(r0 + r) * C + c0 + c] : 0.f;
    t[r * 65 + c] = v;
  }
  __syncthreads();
#pragma unroll
  for (int q = 0; q < 16; q++) {
    int idx = q * 256 + tid;
    int r = idx >> 6, c = idx & 63;
    if (c0 + r < C && r0 + c < R) dst[(size_t)(c0 + r) * R + r0 + c] = t[c * 65 + r];
  }
  __syncthreads();
}

// split one 32x32 tile of x(t) into XA (h/m/l) and XB (h/m/l).
// reads dense from xall when available (R7 read input at stride 32B: 8x
// overfetch, ~600MB of the 700MB FETCH_SIZE), else strided from input.
__device__ __forceinline__ void split_x_tile(const float* __restrict__ in,
                                             const float* __restrict__ xall, int t, int job,
                                             unsigned short* XAh, unsigned short* XAm,
                                             unsigned short* XAl, unsigned short* XBh,
                                             unsigned short* XBm, unsigned short* XBl,
                                             unsigned short* sm /*3*1056*/, int tid) {
  int it = job % 73, bt = job / 73;
  int i0 = it * 32, b0 = bt * 32;
  int il = tid & 31, q0 = tid >> 5;
#pragma unroll
  for (int q = 0; q < 4; q++) {
    int bl = q0 + q * 8;
    int b = b0 + bl, i = i0 + il;
    float v = 0.f;
    if (b < BATCH && i < IN_DIM)
      v = xall ? xall[((size_t)t * BATCH + b) * IN_DIM + i]
               : in[(((size_t)b * IN_DIM + i) << 3) + t];
    unsigned short vh, vm, vl;
    split3(v, vh, vm, vl);
    size_t ax = (size_t)(b0 + bl) * KPAD + i;
    XAh[ax] = vh; XAm[ax] = vm; XAl[ax] = vl;
    sm[0 * 1056 + bl * 33 + il] = vh;
    sm[1 * 1056 + bl * 33 + il] = vm;
    sm[2 * 1056 + bl * 33 + il] = vl;
  }
  __syncthreads();
#pragma unroll
  for (int q = 0; q < 4; q++) {
    int il2 = q0 + q * 8;
    int bl2 = il;
    size_t bx = (size_t)(i0 + il2) * BPAD + b0 + bl2;
    XBh[bx] = sm[0 * 1056 + bl2 * 33 + il2];
    XBm[bx] = sm[1 * 1056 + bl2 * 33 + il2];
    XBl[bx] = sm[2 * 1056 + bl2 * 33 + il2];
  }
  __syncthreads();
}

// GEMM1 tile job: part[s] = XA(64 rows) x Wc(128 cols), K-chunk s
__device__ __forceinline__ void gemm1_body(
    int job, const unsigned short* __restrict__ XAh, const unsigned short* __restrict__ XAm,
    const unsigned short* __restrict__ XAl, const unsigned short* __restrict__ Wch,
    const unsigned short* __restrict__ Wcm, const unsigned short* __restrict__ Wcl,
    float* __restrict__ part, unsigned short* sm, int tid) {
  unsigned short* Ab = sm;          // [3][64*40]
  unsigned short* Bb = sm + 7680;   // [3][128*40]
  int s = job / 28, rr = job % 28;
  int m0 = (rr / 7) * 64, n0 = (rr % 7) * 128;
  int it0 = s * 9, it1 = (s == NS1 - 1) ? 73 : it0 + 9;
  int r = tid >> 2, g = tid & 3;
  int w = tid >> 6, lane = tid & 63;
  int wm = w >> 1, wn = w & 1, lr = lane & 15, lg = lane >> 4;
  f32x4 acc[2][4] = {};
  for (int it = it0; it < it1; ++it) {
    int k0 = it * 32;
    size_t ga = (size_t)(m0 + r) * KPAD + k0 + g * 8;
    uint4 a0 = *(const uint4*)&XAh[ga];
    uint4 a1 = *(const uint4*)&XAm[ga];
    uint4 a2 = *(const uint4*)&XAl[ga];
    size_t gb0 = (size_t)(n0 + r) * KPAD + k0 + g * 8;
    size_t gb1 = gb0 + (size_t)64 * KPAD;
    uint4 b0 = *(const uint4*)&Wch[gb0];
    uint4 b1 = *(const uint4*)&Wcm[gb0];
    uint4 b2 = *(const uint4*)&Wcl[gb0];
    uint4 b3 = *(const uint4*)&Wch[gb1];
    uint4 b4 = *(const uint4*)&Wcm[gb1];
    uint4 b5 = *(const uint4*)&Wcl[gb1];
    __syncthreads();
    int la = r * 40 + g * 8;
    *(uint4*)&Ab[0 * 2560 + la] = a0; *(uint4*)&Ab[1 * 2560 + la] = a1; *(uint4*)&Ab[2 * 2560 + la] = a2;
    *(uint4*)&Bb[0 * 5120 + la] = b0; *(uint4*)&Bb[1 * 5120 + la] = b1; *(uint4*)&Bb[2 * 5120 + la] = b2;
    int lb = la + 2560;
    *(uint4*)&Bb[0 * 5120 + lb] = b3; *(uint4*)&Bb[1 * 5120 + lb] = b4; *(uint4*)&Bb[2 * 5120 + lb] = b5;
    __syncthreads();
    bf16x8 ah[2], am[2], al[2];
#pragma unroll
    for (int fm = 0; fm < 2; fm++) {
      int row = (wm * 32 + fm * 16 + lr) * 40 + lg * 8;
      ah[fm] = *(const bf16x8*)&Ab[0 * 2560 + row];
      am[fm] = *(const bf16x8*)&Ab[1 * 2560 + row];
      al[fm] = *(const bf16x8*)&Ab[2 * 2560 + row];
    }
#pragma unroll
    for (int fn = 0; fn < 4; fn++) {
      int rown = (wn * 64 + fn * 16 + lr) * 40 + lg * 8;
      bf16x8 bh = *(const bf16x8*)&Bb[0 * 5120 + rown];
      bf16x8 bm = *(const bf16x8*)&Bb[1 * 5120 + rown];
      bf16x8 bl = *(const bf16x8*)&Bb[2 * 5120 + rown];
#pragma unroll
      for (int fm = 0; fm < 2; fm++) {
        f32x4 c = acc[fm][fn];
        c = __builtin_amdgcn_mfma_f32_16x16x32_bf16(ah[fm], bh, c, 0, 0, 0);
        c = __builtin_amdgcn_mfma_f32_16x16x32_bf16(ah[fm], bm, c, 0, 0, 0);
        c = __builtin_amdgcn_mfma_f32_16x16x32_bf16(am[fm], bh, c, 0, 0, 0);
        c = __builtin_amdgcn_mfma_f32_16x16x32_bf16(ah[fm], bl, c, 0, 0, 0);
        c = __builtin_amdgcn_mfma_f32_16x16x32_bf16(al[fm], bh, c, 0, 0, 0);
        c = __builtin_amdgcn_mfma_f32_16x16x32_bf16(am[fm], bm, c, 0, 0, 0);
        acc[fm][fn] = c;
      }
    }
  }
  float* pp = part + (size_t)s * (BATCH * HD1);
#pragma unroll
  for (int fm = 0; fm < 2; fm++)
#pragma unroll
    for (int fn = 0; fn < 4; fn++) {
      int n = n0 + wn * 64 + fn * 16 + lr;
      if (n >= HD1) continue;
      int mb = m0 + wm * 32 + fm * 16 + lg * 4;
#pragma unroll
      for (int r4 = 0; r4 < 4; r4++) {
        int m = mb + r4;
        if (m < BATCH) pp[(size_t)m * HD1 + n] = acc[fm][fn][r4];
      }
    }
}

// GEMM2 tile job + hebb1(H)/Wc-split epilogue
__device__ __forceinline__ void gemm2_body(
    int job, const unsigned short* __restrict__ PTh, const unsigned short* __restrict__ PTm,
    const unsigned short* __restrict__ PTl, const unsigned short* __restrict__ XBh,
    const unsigned short* __restrict__ XBm, const unsigned short* __restrict__ XBl,
    const float* __restrict__ beta1, const float* __restrict__ W1,
    const float* __restrict__ alpha1, float* __restrict__ H,
    unsigned short* __restrict__ Wch, unsigned short* __restrict__ Wcm,
    unsigned short* __restrict__ Wcl, unsigned short* sm, int tid) {
  unsigned short* Ab = sm;
  unsigned short* Bb = sm + 7680;
  int m0 = (job / 19) * 64, n0 = (job % 19) * 128;
  int r = tid >> 2, g = tid & 3;
  int w = tid >> 6, lane = tid & 63;
  int wm = w >> 1, wn = w & 1, lr = lane & 15, lg = lane >> 4;
  f32x4 acc[2][4] = {};
  for (int it = 0; it < 7; ++it) {
    int k0 = it * 32;
    size_t ga = (size_t)(m0 + r) * BPAD + k0 + g * 8;
    uint4 a0 = *(const uint4*)&PTh[ga];
    uint4 a1 = *(const uint4*)&PTm[ga];
    uint4 a2 = *(const uint4*)&PTl[ga];
    size_t gb0 = (size_t)(n0 + r) * BPAD + k0 + g * 8;
    size_t gb1 = gb0 + (size_t)64 * BPAD;
    uint4 b0 = *(const uint4*)&XBh[gb0];
    uint4 b1 = *(const uint4*)&XBm[gb0];
    uint4 b2 = *(const uint4*)&XBl[gb0];
    uint4 b3 = *(const uint4*)&XBh[gb1];
    uint4 b4 = *(const uint4*)&XBm[gb1];
    uint4 b5 = *(const uint4*)&XBl[gb1];
    __syncthreads();
    int la = r * 40 + g * 8;
    *(uint4*)&Ab[0 * 2560 + la] = a0; *(uint4*)&Ab[1 * 2560 + la] = a1; *(uint4*)&Ab[2 * 2560 + la] = a2;
    *(uint4*)&Bb[0 * 5120 + la] = b0; *(uint4*)&Bb[1 * 5120 + la] = b1; *(uint4*)&Bb[2 * 5120 + la] = b2;
    int lb = la + 2560;
    *(uint4*)&Bb[0 * 5120 + lb] = b3; *(uint4*)&Bb[1 * 5120 + lb] = b4; *(uint4*)&Bb[2 * 5120 + lb] = b5;
    __syncthreads();
    bf16x8 ah[2], am[2], al[2];
#pragma unroll
    for (int fm = 0; fm < 2; fm++) {
      int row = (wm * 32 + fm * 16 + lr) * 40 + lg * 8;
      ah[fm] = *(const bf16x8*)&Ab[0 * 2560 + row];
      am[fm] = *(const bf16x8*)&Ab[1 * 2560 + row];
      al[fm] = *(const bf16x8*)&Ab[2 * 2560 + row];
    }
#pragma unroll
    for (int fn = 0; fn < 4; fn++) {
      int rown = (wn * 64 + fn * 16 + lr) * 40 + lg * 8;
      bf16x8 bh = *(const bf16x8*)&Bb[0 * 5120 + rown];
      bf16x8 bm = *(const bf16x8*)&Bb[1 * 5120 + rown];
      bf16x8 bl = *(const bf16x8*)&Bb[2 * 5120 + rown];
#pragma unroll
      for (int fm = 0; fm < 2; fm++) {
        f32x4 c = acc[fm][fn];
        c = __builtin_amdgcn_mfma_f32_16x16x32_bf16(ah[fm], bh, c, 0, 0, 0);
        c = __builtin_amdgcn_mfma_f32_16x16x32_bf16(ah[fm], bm, c, 0, 0, 0);
        c = __builtin_amdgcn_mfma_f32_16x16x32_bf16(am[fm], bh, c, 0, 0, 0);
        c = __builtin_amdgcn_mfma_f32_16x16x32_bf16(ah[fm], bl, c, 0, 0, 0);
        c = __builtin_amdgcn_mfma_f32_16x16x32_bf16(al[fm], bh, c, 0, 0, 0);
        c = __builtin_amdgcn_mfma_f32_16x16x32_bf16(am[fm], bm, c, 0, 0, 0);
        acc[fm][fn] = c;
      }
    }
  }
  float al1 = alpha1[0];
#pragma unroll
  for (int fm = 0; fm < 2; fm++)
#pragma unroll
    for (int fn = 0; fn < 4; fn++) {
      int i = n0 + wn * 64 + fn * 16 + lr;
      if (i >= IN_DIM) continue;
      float bc = fmaxf(beta1[i], 0.f);
      int jb = m0 + wm * 32 + fm * 16 + lg * 4;
#pragma unroll
      for (int r4 = 0; r4 < 4; r4++) {
        int j = jb + r4;
        if (j >= HD1) continue;
        size_t hx = (size_t)j * IN_DIM + i;
        float h = 0.99f * H[hx] - bc * acc[fm][fn][r4] * (1.f / 200.f);
        h = fminf(fmaxf(h, -5.f), 5.f);
        H[hx] = h;
        unsigned short vh, vm, vl;
        split3(W1[hx] + al1 * h, vh, vm, vl);
        size_t wx = (size_t)j * KPAD + i;
        Wch[wx] = vh; Wcm[wx] = vm; Wcl[wx] = vl;
      }
    }
}

// ---------------------------------------------------------------------------
// barrier init: zero all flag lines + gen (ws poisoned 0xAA; poisoned flags
// would satisfy the >= compare and break the barrier)
// ---------------------------------------------------------------------------
__global__ void k_bar_init(unsigned* bar) {
  for (int k = threadIdx.x; k < NBLK * FLAG_STRIDE + FLAG_STRIDE; k += 256) bar[k] = 0u;
}

// ---------------------------------------------------------------------------
// the mega-kernel
// ---------------------------------------------------------------------------
__global__ __launch_bounds__(256, 1) void k_mega(Params p) {
  __shared__ __align__(16) unsigned char smem_raw[46080];
  unsigned short* sm_us = (unsigned short*)smem_raw;
  float* sm_f = (float*)smem_raw;
  unsigned* flags = p.flags;
  unsigned* gen = p.gen;
  unsigned bar_no = 0;
  int tid = threadIdx.x, bid = blockIdx.x;
  int gtid = bid * 256 + tid;
  int gwave = (gtid >> 6);

  // ============ phase A: zero pads, init states, H = hebb1_in^T, xall ============
  {
    uint4* z = (uint4*)p.XAh;
    for (int k = gtid; k < ZERO_UINT4; k += 65536) z[k] = make_uint4(0, 0, 0, 0);
    for (int k = gtid; k < BATCH * HD1; k += 65536) { p.mem1[k] = 0.f; p.spike1[k] = 0.f; }
    for (int k = gtid; k < HD1 * HD2; k += 65536) p.hebb2o[k] = p.hebb2_in[k];
    if (gtid < BATCH * HD2) { p.mem2[gtid] = 0.f; p.spike2[gtid] = 0.f; p.post2[gtid] = 0.f; }
    if (p.xall) {
      // input [B][IN_DIM][T] -> xall [T][B][IN_DIM], dense reads (one pass)
      for (int job = bid; job < BATCH * 37; job += NBLK) {
        int b = job / 37, i0 = (job % 37) * 64;
        size_t base = ((size_t)b * IN_DIM + i0) * 8;
#pragma unroll
        for (int q = 0; q < 2; q++) {
          int e = q * 256 + tid;
          int il = e >> 3, t = e & 7;
          float v = (i0 + il < IN_DIM) ? p.input[base + e] : 0.f;
          sm_f[il * 9 + t] = v;
        }
        __syncthreads();
#pragma unroll
        for (int q = 0; q < 2; q++) {
          int e = q * 256 + tid;
          int t2 = e >> 6, il2 = e & 63;
          int i = i0 + il2;
          if (i < IN_DIM)
            p.xall[((size_t)t2 * BATCH + b) * IN_DIM + i] = sm_f[il2 * 9 + t2];
        }
        __syncthreads();
      }
    }
    for (int job = bid; job < 37 * 13; job += NBLK)
      tile_tr(p.hebb1_in, IN_DIM, HD1, p.H, (job / 13) * 64, (job % 13) * 64, sm_f, tid);
  }
  gsync(flags, gen, ++bar_no);

  // ============ phase B: initial Wc split ============
  {
    float al = p.alpha1[0];
    for (int id = gtid; id < HD1 * (IN_DIM / 8); id += 65536) {
      int j = id / (IN_DIM / 8);
      int i8 = (id % (IN_DIM / 8)) * 8;
      size_t sx = (size_t)j * IN_DIM + i8;
      size_t dx = (size_t)j * KPAD + i8;
#pragma unroll
      for (int q = 0; q < 8; q++) {
        unsigned short vh, vm, vl;
        split3(p.W1[sx + q] + al * p.H[sx + q], vh, vm, vl);
        p.Wch[dx + q] = vh; p.Wcm[dx + q] = vm; p.Wcl[dx + q] = vl;
      }
    }
  }
  gsync(flags, gen, ++bar_no);

  // ============ timestep loop ============
  for (int t = 0; t < TWIN; t++) {
    // ---- P0: x-split(t) ----
    for (int job = bid; job < 511; job += NBLK)
      split_x_tile(p.input, p.xall, t, job, p.XAh, p.XAm, p.XAl,
                   p.XBh, p.XBm, p.XBl, sm_us, tid);
    gsync(flags, gen, ++bar_no);

    // ---- P1: GEMM1 (224 jobs) ----
    if (bid < 224)
      gemm1_body(bid, p.XAh, p.XAm, p.XAl, p.Wch, p.Wcm, p.Wcl, p.part, sm_us, tid);
    gsync(flags, gen, ++bar_no);

    // ---- P2: split-K reduce + membrane + PT splits ----
    if (gtid < BATCH * (HD1 / 4)) {
      int m = gtid / (HD1 / 4);
      int n4 = (gtid % (HD1 / 4)) * 4;
      size_t idx = (size_t)m * HD1 + n4;
      float4 sum = *(const float4*)&p.part[idx];
#pragma unroll
      for (int s = 1; s < NS1; s++) {
        float4 q4 = *(const float4*)&p.part[(size_t)s * BATCH * HD1 + idx];
        sum.x += q4.x; sum.y += q4.y; sum.z += q4.z; sum.w += q4.w;
      }
      float4 bb = *(const float4*)&p.b1[n4];
      float4 ee = *(const float4*)&p.eta1[n4];
      float4 mo = *(const float4*)&p.mem1[idx];
      float4 so = *(const float4*)&p.spike1[idx];
      float st[4]  = {sum.x + bb.x, sum.y + bb.y, sum.z + bb.z, sum.w + bb.w};
      float mof[4] = {mo.x, mo.y, mo.z, mo.w};
      float sof[4] = {so.x, so.y, so.z, so.w};
      float eef[4] = {ee.x, ee.y, ee.z, ee.w};
      float mn[4], sp[4];
#pragma unroll
      for (int q = 0; q < 4; q++) {
        mn[q] = mof[q] * (1.f - sof[q]) * 0.25f + st[q];
        sp[q] = (mn[q] - 0.4f > 0.f) ? 1.f : 0.f;
        float po = mn[q] * 2.5f - eef[q];
        unsigned short vh, vm, vl;
        split3(po, vh, vm, vl);
        size_t px = (size_t)(n4 + q) * BPAD + m;
        p.PTh[px] = vh; p.PTm[px] = vm; p.PTl[px] = vl;
      }
      *(float4*)&p.mem1[idx]   = make_float4(mn[0], mn[1], mn[2], mn[3]);
      *(float4*)&p.spike1[idx] = make_float4(sp[0], sp[1], sp[2], sp[3]);
    }
    gsync(flags, gen, ++bar_no);

    // ---- P3: layer-2 state ----
    {
      float al2 = p.alpha2[0];
      int lane = tid & 63;
      for (int wid = gwave; wid < BATCH * HD2; wid += 1024) {
        int b = wid / HD2, j = wid % HD2;
        float acc = 0.f;
        for (int i = lane; i < HD1; i += 64)
          acc += p.spike1[b * HD1 + i] * (p.W2[j * HD1 + i] + al2 * p.hebb2o[i * HD2 + j]);
#pragma unroll
        for (int off = 32; off > 0; off >>= 1) acc += __shfl_down(acc, off, 64);
        if (lane == 0) {
          float state = acc + p.b2[j];
          int idx = b * HD2 + j;
          float mo = p.mem2[idx], so = p.spike2[idx];
          float mnv = mo * (1.f - so) * 0.25f + state;
          p.mem2[idx]   = mnv;
          p.spike2[idx] = (mnv - 0.4f > 0.f) ? 1.f : 0.f;
          p.post2[idx]  = mnv * 2.5f - p.eta2[j];
          p.outs[idx]   = mnv * 2.5f;
        }
      }
    }
    gsync(flags, gen, ++bar_no);

    // ---- P4: GEMM2 + hebb1/Wc epilogue (247 jobs) || hebb2 (9 blocks) ----
    if (bid < 247) {
      gemm2_body(bid, p.PTh, p.PTm, p.PTl, p.XBh, p.XBm, p.XBl, p.beta1, p.W1,
                 p.alpha1, p.H, p.Wch, p.Wcm, p.Wcl, sm_us, tid);
    } else {
      int lid = (bid - 247) * 256 + tid;
      for (int idx = lid; idx < HD1 * HD2; idx += 2304) {
        int i = idx % HD1, j = idx / HD1;
        float acc = 0.f;
        for (int b = 0; b < BATCH; b++)
          acc += p.spike1[b * HD1 + i] * p.post2[b * HD2 + j];
        float bc = fmaxf(p.beta2[i], 0.f);
        float h = 0.99f * p.hebb2o[i * HD2 + j] - bc * acc * (1.f / 200.f);
        p.hebb2o[i * HD2 + j] = fminf(fmaxf(h, -5.f), 5.f);
      }
    }
    gsync(flags, gen, ++bar_no);
  }

  // ============ final: hebb1out = H^T ============
  for (int job = bid; job < 13 * 37; job += NBLK)
    tile_tr(p.H, HD1, IN_DIM, p.hebb1out, (job / 37) * 64, (job % 37) * 64, sm_f, tid);
}

// ---------------------------------------------------------------------------
extern "C" void kernel_launch(void* const* d_in, const int* in_sizes, int n_in,
                              void* d_out, int out_size, void* d_ws, size_t ws_size,
                              hipStream_t stream) {
  Params p;
  p.input    = (const float*)d_in[0];
  p.hebb1_in = (const float*)d_in[1];
  p.hebb2_in = (const float*)d_in[2];
  p.W1       = (const float*)d_in[3];
  p.b1       = (const float*)d_in[4];
  p.W2       = (const float*)d_in[5];
  p.b2       = (const float*)d_in[6];
  p.alpha1   = (const float*)d_in[7];
  p.alpha2   = (const float*)d_in[8];
  p.beta1    = (const float*)d_in[9];
  p.beta2    = (const float*)d_in[10];
  p.eta1     = (const float*)d_in[11];
  p.eta2     = (const float*)d_in[12];

  float* out = (float*)d_out;
  p.outs     = out;
  p.hebb1out = out + BATCH * HD2;
  p.hebb2o   = p.hebb1out + (size_t)IN_DIM * HD1;

  // ws layout: [0, BAR_BYTES) flags+gen; ushort split arrays; fp arrays; xall
  p.flags = (unsigned*)d_ws;
  p.gen   = p.flags + NBLK * FLAG_STRIDE;
  unsigned short* us = (unsigned short*)((char*)d_ws + BAR_BYTES);
  p.XAh = us;
  p.XAm = p.XAh + PLA;
  p.XAl = p.XAm + PLA;
  p.XBh = p.XAl + PLA;
  p.XBm = p.XBh + PLB;
  p.XBl = p.XBm + PLB;
  p.Wch = p.XBl + PLB;
  p.Wcm = p.Wch + NK;
  p.Wcl = p.Wcm + NK;
  p.PTh = p.Wcl + NK;
  p.PTm = p.PTh + JB;
  p.PTl = p.PTm + JB;
  size_t us_total = 3 * (PLA + PLB + NK + JB);   // 10,266,624

  float* fp = (float*)(us + us_total);
  p.part   = fp;
  p.H      = p.part + (size_t)NS1 * BATCH * HD1;
  p.mem1   = p.H + (size_t)HD1 * IN_DIM;
  p.spike1 = p.mem1 + BATCH * HD1;
  p.mem2   = p.spike1 + BATCH * HD1;
  p.spike2 = p.mem2 + BATCH * HD2;
  p.post2  = p.spike2 + BATCH * HD2;

  // xall (fp32 [T][B][IN_DIM]) only if ws has room; else strided-input fallback
  p.xall = (ws_size >= (size_t)WS_NEEDED) ? (float*)((char*)d_ws + WS_BASE) : nullptr;

  k_bar_init<<<1, 256, 0, stream>>>(p.flags);
  k_mega<<<NBLK, 256, 0, stream>>>(p);
}

// Round 9
// 3612.857 us; speedup vs baseline: 2.6448x; 2.2049x over previous
//
#include <hip/hip_runtime.h>

#define BATCH  200
#define IN_DIM 2312
#define HD1    800
#define HD2    10
#define TWIN   8

#define KPAD   2336
#define NPAD   896
#define BPAD   224
#define N2PAD  2432
#define NS1    8

#define PLB    ((size_t)N2PAD * BPAD)   // 544768  (one XB plane)
#define NK     ((size_t)NPAD * KPAD)    // 2093056 (one Wc plane)
// us area = 3*PLB + 3*NK = 7,913,472 ushorts = 989,184 uint4 exactly
#define ZERO_UINT4 989184

typedef __attribute__((ext_vector_type(8))) short bf16x8;
typedef __attribute__((ext_vector_type(4))) float f32x4;

__device__ __forceinline__ unsigned short f2bf(float x) {
  unsigned u = __builtin_bit_cast(unsigned, x);
  u = (u + 0x7FFFu + ((u >> 16) & 1u)) >> 16;
  return (unsigned short)u;
}
__device__ __forceinline__ float bf2f(unsigned short h) {
  unsigned u = ((unsigned)h) << 16;
  return __builtin_bit_cast(float, u);
}
// exact 3-way split: x = hi + mid + lo + O(2^-24 |x|)
__device__ __forceinline__ void split3(float x, unsigned short& h, unsigned short& m,
                                       unsigned short& l) {
  h = f2bf(x);
  float r1 = x - bf2f(h);
  m = f2bf(r1);
  float r2 = r1 - bf2f(m);
  l = f2bf(r2);
}
__device__ __forceinline__ uint4 pack8(const unsigned short* v) {
  return make_uint4((unsigned)v[0] | ((unsigned)v[1] << 16),
                    (unsigned)v[2] | ((unsigned)v[3] << 16),
                    (unsigned)v[4] | ((unsigned)v[5] << 16),
                    (unsigned)v[6] | ((unsigned)v[7] << 16));
}

// ---------------------------------------------------------------------------
// k_pre: zero us pads, build xall [T][B][IN_DIM] (dense input reads),
//        H = hebb1_in^T, init state buffers (ping-pong slot 0), h2buf[0] copy
// ---------------------------------------------------------------------------
__global__ __launch_bounds__(256) void k_pre(const float* __restrict__ input,
                                             const float* __restrict__ hebb1_in,
                                             const float* __restrict__ hebb2_in,
                                             uint4* __restrict__ us_zero,
                                             float* __restrict__ xall,
                                             float* __restrict__ H,
                                             float* __restrict__ mem1_0,
                                             float* __restrict__ spike1_0,
                                             float* __restrict__ mem2_0,
                                             float* __restrict__ spike2_0,
                                             float* __restrict__ h2_0) {
  __shared__ float smf[64 * 65];
  int tid = threadIdx.x, bid = blockIdx.x;
  int gtid = bid * 256 + tid;
  for (int k = gtid; k < ZERO_UINT4; k += 65536) us_zero[k] = make_uint4(0, 0, 0, 0);
  for (int k = gtid; k < BATCH * HD1; k += 65536) { mem1_0[k] = 0.f; spike1_0[k] = 0.f; }
  for (int k = gtid; k < HD1 * HD2; k += 65536) h2_0[k] = hebb2_in[k];
  if (gtid < BATCH * HD2) { mem2_0[gtid] = 0.f; spike2_0[gtid] = 0.f; }
  // xall: input [B][IN_DIM][T] -> [T][B][IN_DIM], dense 2KB reads per job
  for (int job = bid; job < BATCH * 37; job += 256) {
    int b = job / 37, i0 = (job % 37) * 64;
    size_t base = ((size_t)b * IN_DIM + i0) * 8;
#pragma unroll
    for (int q = 0; q < 2; q++) {
      int e = q * 256 + tid;
      int il = e >> 3, t = e & 7;
      float v = (i0 + il < IN_DIM) ? input[base + e] : 0.f;
      smf[il * 9 + t] = v;
    }
    __syncthreads();
#pragma unroll
    for (int q = 0; q < 2; q++) {
      int e = q * 256 + tid;
      int t2 = e >> 6, il2 = e & 63;
      int i = i0 + il2;
      if (i < IN_DIM) xall[((size_t)t2 * BATCH + b) * IN_DIM + i] = smf[il2 * 9 + t2];
    }
    __syncthreads();
  }
  // H[j][i] = hebb1_in[i][j]
  for (int job = bid; job < 37 * 13; job += 256) {
    int r0 = (job / 13) * 64, c0 = (job % 13) * 64;
#pragma unroll
    for (int q = 0; q < 16; q++) {
      int idx = q * 256 + tid;
      int r = idx >> 6, c = idx & 63;
      float v = (r0 + r < IN_DIM && c0 + c < HD1) ? hebb1_in[(size_t)(r0 + r) * HD1 + c0 + c] : 0.f;
      smf[r * 65 + c] = v;
    }
    __syncthreads();
#pragma unroll
    for (int q = 0; q < 16; q++) {
      int idx = q * 256 + tid;
      int r = idx >> 6, c = idx & 63;
      if (c0 + r < HD1 && r0 + c < IN_DIM)
        H[(size_t)(c0 + r) * IN_DIM + r0 + c] = smf[c * 65 + r];
    }
    __syncthreads();
  }
}

// ---------------------------------------------------------------------------
// XB build for one 32x32 tile of x(t): xall dense -> XB planes [i][b]
// ---------------------------------------------------------------------------
__device__ __forceinline__ void xb_tile(const float* __restrict__ xt, int job,
                                        unsigned short* __restrict__ XBh,
                                        unsigned short* __restrict__ XBm,
                                        unsigned short* __restrict__ XBl,
                                        unsigned short* sm /*3*1056*/, int tid) {
  int it = job % 73, bt = job / 73;
  int i0 = it * 32, b0 = bt * 32;
  int il = tid & 31, q0 = tid >> 5;
#pragma unroll
  for (int q = 0; q < 4; q++) {
    int bl = q0 + q * 8;
    int b = b0 + bl, i = i0 + il;
    float v = (b < BATCH && i < IN_DIM) ? xt[(size_t)b * IN_DIM + i] : 0.f;
    unsigned short vh, vm, vl;
    split3(v, vh, vm, vl);
    sm[0 * 1056 + bl * 33 + il] = vh;
    sm[1 * 1056 + bl * 33 + il] = vm;
    sm[2 * 1056 + bl * 33 + il] = vl;
  }
  __syncthreads();
#pragma unroll
  for (int q = 0; q < 4; q++) {
    int il2 = q0 + q * 8;    // i-local
    int bl2 = il;            // b-local
    size_t bx = (size_t)(i0 + il2) * BPAD + b0 + bl2;
    XBh[bx] = sm[0 * 1056 + bl2 * 33 + il2];
    XBm[bx] = sm[1 * 1056 + bl2 * 33 + il2];
    XBl[bx] = sm[2 * 1056 + bl2 * 33 + il2];
  }
  __syncthreads();
}

// ---------------------------------------------------------------------------
// k_pre2: initial Wc split (Wc[j][i] = W1 + a1*H) + XB(0) build
// ---------------------------------------------------------------------------
__global__ __launch_bounds__(256) void k_pre2(const float* __restrict__ W1,
                                              const float* __restrict__ H,
                                              const float* __restrict__ alpha1,
                                              const float* __restrict__ xall,
                                              unsigned short* __restrict__ Wch,
                                              unsigned short* __restrict__ Wcm,
                                              unsigned short* __restrict__ Wcl,
                                              unsigned short* __restrict__ XBh,
                                              unsigned short* __restrict__ XBm,
                                              unsigned short* __restrict__ XBl) {
  __shared__ unsigned short smx[3 * 1056];
  int tid = threadIdx.x, bid = blockIdx.x;
  int gtid = bid * 256 + tid;
  float al = alpha1[0];
  for (int id = gtid; id < HD1 * (IN_DIM / 8); id += 65536) {
    int j = id / (IN_DIM / 8);
    int i8 = (id % (IN_DIM / 8)) * 8;
    size_t sx = (size_t)j * IN_DIM + i8;
    size_t dx = (size_t)j * KPAD + i8;
#pragma unroll
    for (int q = 0; q < 8; q++) {
      unsigned short vh, vm, vl;
      split3(W1[sx + q] + al * H[sx + q], vh, vm, vl);
      Wch[dx + q] = vh; Wcm[dx + q] = vm; Wcl[dx + q] = vl;
    }
  }
  for (int job = bid; job < 511; job += 256)
    xb_tile(xall, job, XBh, XBm, XBl, smx, tid);
}

// ---------------------------------------------------------------------------
// k_gemm1: split-K MFMA GEMM, part[s] = x(t) @ Wc^T-ish.
// A staged inline from fp32 xall (split3 on the fly); B from Wc bf16 planes.
// grid (4,7,8): m0=bx*64, n0=by*128, s=bz.
// ---------------------------------------------------------------------------
__global__ __launch_bounds__(256) void k_gemm1(const float* __restrict__ xt,
                                               const unsigned short* __restrict__ Wch,
                                               const unsigned short* __restrict__ Wcm,
                                               const unsigned short* __restrict__ Wcl,
                                               float* __restrict__ part) {
  __shared__ __align__(16) unsigned short Ab[3][2560];   // [64 rows][40]
  __shared__ __align__(16) unsigned short Bb[3][5120];   // [128 rows][40]
  int m0 = blockIdx.x * 64, n0 = blockIdx.y * 128, s = blockIdx.z;
  int it0 = s * 9, it1 = (s == NS1 - 1) ? 73 : it0 + 9;
  int tid = threadIdx.x;
  int r = tid >> 2, g = tid & 3;
  int w = tid >> 6, lane = tid & 63;
  int wm = w >> 1, wn = w & 1, lr = lane & 15, lg = lane >> 4;
  f32x4 acc[2][4] = {};
  for (int it = it0; it < it1; ++it) {
    int k0 = it * 32;
    // A: read 8 fp32 from xall, split3 -> 3 packed uint4
    unsigned short hh[8], mm[8], ll[8];
    {
      int m = m0 + r, kk = k0 + g * 8;
      float xv[8] = {};
      if (m < BATCH && kk + 8 <= IN_DIM) {
        float4 x0 = *(const float4*)&xt[(size_t)m * IN_DIM + kk];
        float4 x1 = *(const float4*)&xt[(size_t)m * IN_DIM + kk + 4];
        xv[0] = x0.x; xv[1] = x0.y; xv[2] = x0.z; xv[3] = x0.w;
        xv[4] = x1.x; xv[5] = x1.y; xv[6] = x1.z; xv[7] = x1.w;
      }
#pragma unroll
      for (int q = 0; q < 8; q++) split3(xv[q], hh[q], mm[q], ll[q]);
    }
    size_t gb0 = (size_t)(n0 + r) * KPAD + k0 + g * 8;
    size_t gb1 = gb0 + (size_t)64 * KPAD;
    uint4 b0 = *(const uint4*)&Wch[gb0];
    uint4 b1 = *(const uint4*)&Wcm[gb0];
    uint4 b2 = *(const uint4*)&Wcl[gb0];
    uint4 b3 = *(const uint4*)&Wch[gb1];
    uint4 b4 = *(const uint4*)&Wcm[gb1];
    uint4 b5 = *(const uint4*)&Wcl[gb1];
    __syncthreads();
    int la = r * 40 + g * 8;
    *(uint4*)&Ab[0][la] = pack8(hh);
    *(uint4*)&Ab[1][la] = pack8(mm);
    *(uint4*)&Ab[2][la] = pack8(ll);
    *(uint4*)&Bb[0][la] = b0; *(uint4*)&Bb[1][la] = b1; *(uint4*)&Bb[2][la] = b2;
    int lb = la + 2560;
    *(uint4*)&Bb[0][lb] = b3; *(uint4*)&Bb[1][lb] = b4; *(uint4*)&Bb[2][lb] = b5;
    __syncthreads();
    bf16x8 ah[2], am[2], al[2];
#pragma unroll
    for (int fm = 0; fm < 2; fm++) {
      int row = (wm * 32 + fm * 16 + lr) * 40 + lg * 8;
      ah[fm] = *(const bf16x8*)&Ab[0][row];
      am[fm] = *(const bf16x8*)&Ab[1][row];
      al[fm] = *(const bf16x8*)&Ab[2][row];
    }
#pragma unroll
    for (int fn = 0; fn < 4; fn++) {
      int rown = (wn * 64 + fn * 16 + lr) * 40 + lg * 8;
      bf16x8 bh = *(const bf16x8*)&Bb[0][rown];
      bf16x8 bm = *(const bf16x8*)&Bb[1][rown];
      bf16x8 bl = *(const bf16x8*)&Bb[2][rown];
#pragma unroll
      for (int fm = 0; fm < 2; fm++) {
        f32x4 c = acc[fm][fn];
        c = __builtin_amdgcn_mfma_f32_16x16x32_bf16(ah[fm], bh, c, 0, 0, 0);
        c = __builtin_amdgcn_mfma_f32_16x16x32_bf16(ah[fm], bm, c, 0, 0, 0);
        c = __builtin_amdgcn_mfma_f32_16x16x32_bf16(am[fm], bh, c, 0, 0, 0);
        c = __builtin_amdgcn_mfma_f32_16x16x32_bf16(ah[fm], bl, c, 0, 0, 0);
        c = __builtin_amdgcn_mfma_f32_16x16x32_bf16(al[fm], bh, c, 0, 0, 0);
        c = __builtin_amdgcn_mfma_f32_16x16x32_bf16(am[fm], bm, c, 0, 0, 0);
        acc[fm][fn] = c;
      }
    }
  }
  float* pp = part + (size_t)s * (BATCH * HD1);
#pragma unroll
  for (int fm = 0; fm < 2; fm++)
#pragma unroll
    for (int fn = 0; fn < 4; fn++) {
      int n = n0 + wn * 64 + fn * 16 + lr;
      if (n >= HD1) continue;
      int mb = m0 + wm * 32 + fm * 16 + lg * 4;
#pragma unroll
      for (int r4 = 0; r4 < 4; r4++) {
        int m = mb + r4;
        if (m < BATCH) pp[(size_t)m * HD1 + n] = acc[fm][fn][r4];
      }
    }
}

// ---------------------------------------------------------------------------
// k_gemm2f: fused epi + GEMM2 + hebb1/Wc epilogue.
// Prologue: rebuild PT tile (64 j-rows x 224 b) in LDS from part + membrane
// update (19x redundant, deterministic; by==0 blocks write mem1/spike1 new).
// GEMM: G[j][i] = PT @ XB^T-ish (K=200pad224). Epilogue: H update + Wc split.
// grid (13,19): m0=bx*64 (j), n0=by*128 (i).
// ---------------------------------------------------------------------------
__global__ __launch_bounds__(256) void k_gemm2f(
    const float* __restrict__ part, const unsigned short* __restrict__ XBh,
    const unsigned short* __restrict__ XBm, const unsigned short* __restrict__ XBl,
    const float* __restrict__ mem_old, const float* __restrict__ spike_old,
    float* __restrict__ mem_new, float* __restrict__ spike_new,
    const float* __restrict__ b1, const float* __restrict__ eta1,
    const float* __restrict__ beta1, const float* __restrict__ W1,
    const float* __restrict__ alpha1, float* __restrict__ H,
    unsigned short* __restrict__ Wch, unsigned short* __restrict__ Wcm,
    unsigned short* __restrict__ Wcl) {
  __shared__ __align__(16) unsigned short PT[3][64 * 232];   // [j-local][b] stride 232
  __shared__ __align__(16) unsigned short Bb[3][5120];       // [128][40]
  int m0 = blockIdx.x * 64, n0 = blockIdx.y * 128;
  bool writer = (blockIdx.y == 0);
  int tid = threadIdx.x;
  int wv = tid >> 6, lane = tid & 63;
  // ---- prologue: PT tile ----
  {
    int j = m0 + lane;
    bool jok = (j < HD1);
    float b1j = jok ? b1[j] : 0.f;
    float e1j = jok ? eta1[j] : 0.f;
    for (int b = wv * 56; b < wv * 56 + 56; ++b) {
      float po = 0.f;
      if (b < BATCH && jok) {
        float ssum = 0.f;
#pragma unroll
        for (int ss = 0; ss < NS1; ss++) ssum += part[(size_t)ss * BATCH * HD1 + b * HD1 + j];
        ssum += b1j;
        size_t ix = (size_t)b * HD1 + j;
        float mo = mem_old[ix], so = spike_old[ix];
        float mnv = mo * (1.f - so) * 0.25f + ssum;
        float sp = (mnv - 0.4f > 0.f) ? 1.f : 0.f;
        po = mnv * 2.5f - e1j;
        if (writer) { mem_new[ix] = mnv; spike_new[ix] = sp; }
      }
      unsigned short vh, vm, vl;
      split3(po, vh, vm, vl);
      PT[0][lane * 232 + b] = vh;
      PT[1][lane * 232 + b] = vm;
      PT[2][lane * 232 + b] = vl;
    }
  }
  int r = tid >> 2, g = tid & 3;
  int w = tid >> 6;
  int wm = w >> 1, wn = w & 1, lr = lane & 15, lg = lane >> 4;
  f32x4 acc[2][4] = {};
  for (int it = 0; it < 7; ++it) {
    int k0 = it * 32;
    size_t gb0 = (size_t)(n0 + r) * BPAD + k0 + g * 8;
    size_t gb1 = gb0 + (size_t)64 * BPAD;
    uint4 b0 = *(const uint4*)&XBh[gb0];
    uint4 b1v = *(const uint4*)&XBm[gb0];
    uint4 b2 = *(const uint4*)&XBl[gb0];
    uint4 b3 = *(const uint4*)&XBh[gb1];
    uint4 b4 = *(const uint4*)&XBm[gb1];
    uint4 b5 = *(const uint4*)&XBl[gb1];
    __syncthreads();
    int la = r * 40 + g * 8;
    *(uint4*)&Bb[0][la] = b0; *(uint4*)&Bb[1][la] = b1v; *(uint4*)&Bb[2][la] = b2;
    int lb = la + 2560;
    *(uint4*)&Bb[0][lb] = b3; *(uint4*)&Bb[1][lb] = b4; *(uint4*)&Bb[2][lb] = b5;
    __syncthreads();
    bf16x8 ah[2], am[2], al[2];
#pragma unroll
    for (int fm = 0; fm < 2; fm++) {
      int row = (wm * 32 + fm * 16 + lr) * 232 + k0 + lg * 8;
      ah[fm] = *(const bf16x8*)&PT[0][row];
      am[fm] = *(const bf16x8*)&PT[1][row];
      al[fm] = *(const bf16x8*)&PT[2][row];
    }
#pragma unroll
    for (int fn = 0; fn < 4; fn++) {
      int rown = (wn * 64 + fn * 16 + lr) * 40 + lg * 8;
      bf16x8 bh = *(const bf16x8*)&Bb[0][rown];
      bf16x8 bm = *(const bf16x8*)&Bb[1][rown];
      bf16x8 bl = *(const bf16x8*)&Bb[2][rown];
#pragma unroll
      for (int fm = 0; fm < 2; fm++) {
        f32x4 c = acc[fm][fn];
        c = __builtin_amdgcn_mfma_f32_16x16x32_bf16(ah[fm], bh, c, 0, 0, 0);
        c = __builtin_amdgcn_mfma_f32_16x16x32_bf16(ah[fm], bm, c, 0, 0, 0);
        c = __builtin_amdgcn_mfma_f32_16x16x32_bf16(am[fm], bh, c, 0, 0, 0);
        c = __builtin_amdgcn_mfma_f32_16x16x32_bf16(ah[fm], bl, c, 0, 0, 0);
        c = __builtin_amdgcn_mfma_f32_16x16x32_bf16(al[fm], bh, c, 0, 0, 0);
        c = __builtin_amdgcn_mfma_f32_16x16x32_bf16(am[fm], bm, c, 0, 0, 0);
        acc[fm][fn] = c;
      }
    }
  }
  float al1 = alpha1[0];
#pragma unroll
  for (int fm = 0; fm < 2; fm++)
#pragma unroll
    for (int fn = 0; fn < 4; fn++) {
      int i = n0 + wn * 64 + fn * 16 + lr;
      if (i >= IN_DIM) continue;
      float bc = fmaxf(beta1[i], 0.f);
      int jb = m0 + wm * 32 + fm * 16 + lg * 4;
#pragma unroll
      for (int r4 = 0; r4 < 4; r4++) {
        int j = jb + r4;
        if (j >= HD1) continue;
        size_t hx = (size_t)j * IN_DIM + i;
        float h = 0.99f * H[hx] - bc * acc[fm][fn][r4] * (1.f / 200.f);
        h = fminf(fmaxf(h, -5.f), 5.f);
        H[hx] = h;
        unsigned short vh, vm, vl;
        split3(W1[hx] + al1 * h, vh, vm, vl);
        size_t wx = (size_t)j * KPAD + i;
        Wch[wx] = vh; Wcm[wx] = vm; Wcl[wx] = vl;
      }
    }
}

// ---------------------------------------------------------------------------
// k_l2h2: blocks 0..39: layer-2 state (redundant post2 in LDS; block 0 writes
// mem2/spike2/outs) + hebb2 slice update (ping-pong h2). blocks 40..295:
// XB(t+1) build (race-free: gemm2f(t) already consumed XB(t)).
// ---------------------------------------------------------------------------
__global__ __launch_bounds__(256) void k_l2h2(
    const float* __restrict__ spike1_new, const float* __restrict__ W2,
    const float* __restrict__ b2, const float* __restrict__ alpha2,
    const float* __restrict__ beta2, const float* __restrict__ eta2,
    const float* __restrict__ mem2_old, const float* __restrict__ spike2_old,
    float* __restrict__ mem2_new, float* __restrict__ spike2_new,
    const float* __restrict__ h2_old, float* __restrict__ h2_new,
    float* __restrict__ outs, float* __restrict__ hebb2out,
    const float* __restrict__ xt_next, int is_last,
    unsigned short* __restrict__ XBh, unsigned short* __restrict__ XBm,
    unsigned short* __restrict__ XBl) {
  __shared__ float post2s[BATCH * HD2];
  __shared__ unsigned short smx[3 * 1056];
  int tid = threadIdx.x, bid = blockIdx.x;
  if (bid < 40) {
    float a2 = alpha2[0];
    for (int p = tid; p < BATCH * HD2; p += 256) {
      int b = p / HD2, j = p % HD2;
      float acc = 0.f;
      const float* sp = &spike1_new[(size_t)b * HD1];
      const float* wr = &W2[(size_t)j * HD1];
      for (int i4 = 0; i4 < HD1 / 4; i4++) {
        float4 sv = *(const float4*)&sp[i4 * 4];
        float4 wv = *(const float4*)&wr[i4 * 4];
        acc += sv.x * (wv.x + a2 * h2_old[(i4 * 4 + 0) * HD2 + j]);
        acc += sv.y * (wv.y + a2 * h2_old[(i4 * 4 + 1) * HD2 + j]);
        acc += sv.z * (wv.z + a2 * h2_old[(i4 * 4 + 2) * HD2 + j]);
        acc += sv.w * (wv.w + a2 * h2_old[(i4 * 4 + 3) * HD2 + j]);
      }
      float state = acc + b2[j];
      float mo = mem2_old[p], so = spike2_old[p];
      float mnv = mo * (1.f - so) * 0.25f + state;
      float spk = (mnv - 0.4f > 0.f) ? 1.f : 0.f;
      post2s[p] = mnv * 2.5f - eta2[j];
      if (bid == 0) { mem2_new[p] = mnv; spike2_new[p] = spk; outs[p] = mnv * 2.5f; }
    }
    __syncthreads();
    if (tid < 200) {
      int i = bid * 20 + tid / 10, j = tid % 10;
      float acc = 0.f;
      for (int b = 0; b < BATCH; b++)
        acc += spike1_new[(size_t)b * HD1 + i] * post2s[b * HD2 + j];
      float bc = fmaxf(beta2[i], 0.f);
      float h = 0.99f * h2_old[i * HD2 + j] - bc * acc * (1.f / 200.f);
      h = fminf(fmaxf(h, -5.f), 5.f);
      h2_new[i * HD2 + j] = h;
      if (is_last) hebb2out[i * HD2 + j] = h;
    }
  } else if (!is_last) {
    int j0 = bid - 40;
    if (j0 < 511) xb_tile(xt_next, j0, XBh, XBm, XBl, smx, tid);
    if (j0 + 256 < 511) xb_tile(xt_next, j0 + 256, XBh, XBm, XBl, smx, tid);
  }
}

// ---------------------------------------------------------------------------
// k_htr: hebb1out = H^T  (H [800][2312] -> [2312][800])
// ---------------------------------------------------------------------------
__global__ __launch_bounds__(256) void k_htr(const float* __restrict__ H,
                                             float* __restrict__ hebb1out) {
  __shared__ float smf[64 * 65];
  int tid = threadIdx.x;
  int job = blockIdx.x;                   // 13*37 = 481
  int r0 = (job / 37) * 64, c0 = (job % 37) * 64;
#pragma unroll
  for (int q = 0; q < 16; q++) {
    int idx = q * 256 + tid;
    int r = idx >> 6, c = idx & 63;
    float v = (r0 + r < HD1 && c0 + c < IN_DIM) ? H[(size_t)(r0 + r) * IN_DIM + c0 + c] : 0.f;
    smf[r * 65 + c] = v;
  }
  __syncthreads();
#pragma unroll
  for (int q = 0; q < 16; q++) {
    int idx = q * 256 + tid;
    int r = idx >> 6, c = idx & 63;
    if (c0 + r < IN_DIM && r0 + c < HD1)
      hebb1out[(size_t)(c0 + r) * HD1 + r0 + c] = smf[c * 65 + r];
  }
}

// ---------------------------------------------------------------------------
extern "C" void kernel_launch(void* const* d_in, const int* in_sizes, int n_in,
                              void* d_out, int out_size, void* d_ws, size_t ws_size,
                              hipStream_t stream) {
  const float* input    = (const float*)d_in[0];
  const float* hebb1_in = (const float*)d_in[1];
  const float* hebb2_in = (const float*)d_in[2];
  const float* W1       = (const float*)d_in[3];
  const float* b1       = (const float*)d_in[4];
  const float* W2       = (const float*)d_in[5];
  const float* b2       = (const float*)d_in[6];
  const float* alpha1   = (const float*)d_in[7];
  const float* alpha2   = (const float*)d_in[8];
  const float* beta1    = (const float*)d_in[9];
  const float* beta2    = (const float*)d_in[10];
  const float* eta1     = (const float*)d_in[11];
  const float* eta2     = (const float*)d_in[12];

  float* out      = (float*)d_out;
  float* outs     = out;                               // [200][10]
  float* hebb1out = out + BATCH * HD2;                 // [2312][800]
  float* hebb2out = hebb1out + (size_t)IN_DIM * HD1;   // [800][10]

  // ws layout: ushort area (XB planes, Wc planes) then fp32 area
  unsigned short* us = (unsigned short*)d_ws;
  unsigned short* XBh = us;
  unsigned short* XBm = XBh + PLB;
  unsigned short* XBl = XBm + PLB;
  unsigned short* Wch = XBl + PLB;
  unsigned short* Wcm = Wch + NK;
  unsigned short* Wcl = Wcm + NK;
  size_t us_total = 3 * (PLB + NK);                    // 7,913,472

  float* fp = (float*)(us + us_total);
  float* part    = fp;                                 // 8*200*800
  float* H       = part + (size_t)NS1 * BATCH * HD1;   // 800*2312
  float* mem1a   = H + (size_t)HD1 * IN_DIM;           // ping-pong pairs
  float* mem1b   = mem1a + BATCH * HD1;
  float* spike1a = mem1b + BATCH * HD1;
  float* spike1b = spike1a + BATCH * HD1;
  float* mem2a   = spike1b + BATCH * HD1;              // 200*10 each
  float* mem2b   = mem2a + BATCH * HD2;
  float* spike2a = mem2b + BATCH * HD2;
  float* spike2b = spike2a + BATCH * HD2;
  float* h2a     = spike2b + BATCH * HD2;              // 800*10 each
  float* h2b     = h2a + HD1 * HD2;
  float* xall    = h2b + HD1 * HD2;                    // 8*200*2312

  float* mem1p[2]   = {mem1a, mem1b};
  float* spike1p[2] = {spike1a, spike1b};
  float* mem2p[2]   = {mem2a, mem2b};
  float* spike2p[2] = {spike2a, spike2b};
  float* h2p[2]     = {h2a, h2b};

  k_pre<<<256, 256, 0, stream>>>(input, hebb1_in, hebb2_in, (uint4*)us, xall, H,
                                 mem1a, spike1a, mem2a, spike2a, h2a);
  k_pre2<<<256, 256, 0, stream>>>(W1, H, alpha1, xall, Wch, Wcm, Wcl, XBh, XBm, XBl);

  for (int t = 0; t < TWIN; t++) {
    const float* xt = xall + (size_t)t * BATCH * IN_DIM;
    int o = t & 1, n = o ^ 1;
    k_gemm1<<<dim3(4, 7, NS1), 256, 0, stream>>>(xt, Wch, Wcm, Wcl, part);
    k_gemm2f<<<dim3(13, 19), 256, 0, stream>>>(part, XBh, XBm, XBl,
                                               mem1p[o], spike1p[o], mem1p[n], spike1p[n],
                                               b1, eta1, beta1, W1, alpha1, H,
                                               Wch, Wcm, Wcl);
    k_l2h2<<<296, 256, 0, stream>>>(spike1p[n], W2, b2, alpha2, beta2, eta2,
                                    mem2p[o], spike2p[o], mem2p[n], spike2p[n],
                                    h2p[o], h2p[n], outs, hebb2out,
                                    xall + (size_t)(t + 1) * BATCH * IN_DIM,
                                    (t == TWIN - 1) ? 1 : 0,
                                    XBh, XBm, XBl);
  }
  k_htr<<<481, 256, 0, stream>>>(H, hebb1out);
}

// Round 10
// 1096.904 us; speedup vs baseline: 8.7113x; 3.2937x over previous
//
#include <hip/hip_runtime.h>

#define BATCH  200
#define IN_DIM 2312
#define HD1    800
#define HD2    10
#define TWIN   8

#define KPAD   2336
#define BPAD   224
#define NS1    8

#define PLB    ((size_t)2432 * BPAD)    // 544768 (one XB plane, N2PAD=2432)
#define NK     ((size_t)896 * KPAD)     // 2093056 (one Wc plane, NPAD=896)
// us area = 6*PLB + 3*NK = 9,547,776 ushorts = 1,193,472 uint4 exactly
#define ZERO_UINT4 1193472

typedef __attribute__((ext_vector_type(8))) short bf16x8;
typedef __attribute__((ext_vector_type(4))) float f32x4;

__device__ __forceinline__ unsigned short f2bf(float x) {
  unsigned u = __builtin_bit_cast(unsigned, x);
  u = (u + 0x7FFFu + ((u >> 16) & 1u)) >> 16;
  return (unsigned short)u;
}
__device__ __forceinline__ float bf2f(unsigned short h) {
  unsigned u = ((unsigned)h) << 16;
  return __builtin_bit_cast(float, u);
}
__device__ __forceinline__ void split3(float x, unsigned short& h, unsigned short& m,
                                       unsigned short& l) {
  h = f2bf(x);
  float r1 = x - bf2f(h);
  m = f2bf(r1);
  float r2 = r1 - bf2f(m);
  l = f2bf(r2);
}
__device__ __forceinline__ uint4 pack8(const unsigned short* v) {
  return make_uint4((unsigned)v[0] | ((unsigned)v[1] << 16),
                    (unsigned)v[2] | ((unsigned)v[3] << 16),
                    (unsigned)v[4] | ((unsigned)v[5] << 16),
                    (unsigned)v[6] | ((unsigned)v[7] << 16));
}

// ---------------------------------------------------------------------------
// k_pre: zero us area, xall [T][B][IN_DIM] (dense input reads), H=hebb1^T,
// init states (slot a)
// ---------------------------------------------------------------------------
__global__ __launch_bounds__(256) void k_pre(const float* __restrict__ input,
                                             const float* __restrict__ hebb1_in,
                                             const float* __restrict__ hebb2_in,
                                             uint4* __restrict__ us_zero,
                                             float* __restrict__ xall,
                                             float* __restrict__ H,
                                             float* __restrict__ mem1_0,
                                             float* __restrict__ spike1_0,
                                             float* __restrict__ mem2_0,
                                             float* __restrict__ spike2_0,
                                             float* __restrict__ h2_0) {
  __shared__ float smf[64 * 65];
  int tid = threadIdx.x, bid = blockIdx.x;
  int gtid = bid * 256 + tid;
  for (int k = gtid; k < ZERO_UINT4; k += 65536) us_zero[k] = make_uint4(0, 0, 0, 0);
  for (int k = gtid; k < BATCH * HD1; k += 65536) { mem1_0[k] = 0.f; spike1_0[k] = 0.f; }
  for (int k = gtid; k < HD1 * HD2; k += 65536) h2_0[k] = hebb2_in[k];
  if (gtid < BATCH * HD2) { mem2_0[gtid] = 0.f; spike2_0[gtid] = 0.f; }
  for (int job = bid; job < BATCH * 37; job += 256) {
    int b = job / 37, i0 = (job % 37) * 64;
    size_t base = ((size_t)b * IN_DIM + i0) * 8;
#pragma unroll
    for (int q = 0; q < 2; q++) {
      int e = q * 256 + tid;
      int il = e >> 3, t = e & 7;
      float v = (i0 + il < IN_DIM) ? input[base + e] : 0.f;
      smf[il * 9 + t] = v;
    }
    __syncthreads();
#pragma unroll
    for (int q = 0; q < 2; q++) {
      int e = q * 256 + tid;
      int t2 = e >> 6, il2 = e & 63;
      int i = i0 + il2;
      if (i < IN_DIM) xall[((size_t)t2 * BATCH + b) * IN_DIM + i] = smf[il2 * 9 + t2];
    }
    __syncthreads();
  }
  for (int job = bid; job < 37 * 13; job += 256) {
    int r0 = (job / 13) * 64, c0 = (job % 13) * 64;
#pragma unroll
    for (int q = 0; q < 16; q++) {
      int idx = q * 256 + tid;
      int r = idx >> 6, c = idx & 63;
      float v = (r0 + r < IN_DIM && c0 + c < HD1) ? hebb1_in[(size_t)(r0 + r) * HD1 + c0 + c] : 0.f;
      smf[r * 65 + c] = v;
    }
    __syncthreads();
#pragma unroll
    for (int q = 0; q < 16; q++) {
      int idx = q * 256 + tid;
      int r = idx >> 6, c = idx & 63;
      if (c0 + r < HD1 && r0 + c < IN_DIM)
        H[(size_t)(c0 + r) * IN_DIM + r0 + c] = smf[c * 65 + r];
    }
    __syncthreads();
  }
}

// ---------------------------------------------------------------------------
// XB tile build: x(t) dense [b][i] -> XB planes [i][b]
// ---------------------------------------------------------------------------
__device__ __forceinline__ void xb_tile(const float* __restrict__ xt, int job,
                                        unsigned short* __restrict__ XBh,
                                        unsigned short* __restrict__ XBm,
                                        unsigned short* __restrict__ XBl,
                                        unsigned short* sm /*>=3*1056*/, int tid) {
  int it = job % 73, bt = job / 73;
  int i0 = it * 32, b0 = bt * 32;
  int il = tid & 31, q0 = tid >> 5;
#pragma unroll
  for (int q = 0; q < 4; q++) {
    int bl = q0 + q * 8;
    int b = b0 + bl, i = i0 + il;
    float v = (b < BATCH && i < IN_DIM) ? xt[(size_t)b * IN_DIM + i] : 0.f;
    unsigned short vh, vm, vl;
    split3(v, vh, vm, vl);
    sm[0 * 1056 + bl * 33 + il] = vh;
    sm[1 * 1056 + bl * 33 + il] = vm;
    sm[2 * 1056 + bl * 33 + il] = vl;
  }
  __syncthreads();
#pragma unroll
  for (int q = 0; q < 4; q++) {
    int il2 = q0 + q * 8;
    int bl2 = il;
    size_t bx = (size_t)(i0 + il2) * BPAD + b0 + bl2;
    XBh[bx] = sm[0 * 1056 + bl2 * 33 + il2];
    XBm[bx] = sm[1 * 1056 + bl2 * 33 + il2];
    XBl[bx] = sm[2 * 1056 + bl2 * 33 + il2];
  }
  __syncthreads();
}

// ---------------------------------------------------------------------------
// k_pre2: initial Wc split + XB(0) build (buffer 0)
// ---------------------------------------------------------------------------
__global__ __launch_bounds__(256) void k_pre2(const float* __restrict__ W1,
                                              const float* __restrict__ H,
                                              const float* __restrict__ alpha1,
                                              const float* __restrict__ xall,
                                              unsigned short* __restrict__ Wch,
                                              unsigned short* __restrict__ Wcm,
                                              unsigned short* __restrict__ Wcl,
                                              unsigned short* __restrict__ XBh,
                                              unsigned short* __restrict__ XBm,
                                              unsigned short* __restrict__ XBl) {
  __shared__ unsigned short smx[3 * 1056];
  int tid = threadIdx.x, bid = blockIdx.x;
  int gtid = bid * 256 + tid;
  float al = alpha1[0];
  for (int id = gtid; id < HD1 * (IN_DIM / 8); id += 65536) {
    int j = id / (IN_DIM / 8);
    int i8 = (id % (IN_DIM / 8)) * 8;
    size_t sx = (size_t)j * IN_DIM + i8;
    size_t dx = (size_t)j * KPAD + i8;
#pragma unroll
    for (int q = 0; q < 8; q++) {
      unsigned short vh, vm, vl;
      split3(W1[sx + q] + al * H[sx + q], vh, vm, vl);
      Wch[dx + q] = vh; Wcm[dx + q] = vm; Wcl[dx + q] = vl;
    }
  }
  for (int job = bid; job < 511; job += 256)
    xb_tile(xall, job, XBh, XBm, XBl, smx, tid);
}

// ---------------------------------------------------------------------------
// gemm1 body: partT[b][j][s] = x(t) @ Wc^T-ish, split-K chunk s.
// A from fp32 xall (inline split3); B from Wc planes. 224 jobs.
// ---------------------------------------------------------------------------
__device__ __forceinline__ void gemm1_body(
    int job, const float* __restrict__ xt,
    const unsigned short* __restrict__ Wch, const unsigned short* __restrict__ Wcm,
    const unsigned short* __restrict__ Wcl, float* __restrict__ partT,
    unsigned short* Ab, unsigned short* Bb, int tid) {
  int s = job / 28, rr = job % 28;
  int m0 = (rr / 7) * 64, n0 = (rr % 7) * 128;
  int it0 = s * 9, it1 = (s == NS1 - 1) ? 73 : it0 + 9;
  int r = tid >> 2, g = tid & 3;
  int w = tid >> 6, lane = tid & 63;
  int wm = w >> 1, wn = w & 1, lr = lane & 15, lg = lane >> 4;
  f32x4 acc[2][4] = {};
  for (int it = it0; it < it1; ++it) {
    int k0 = it * 32;
    unsigned short hh[8], mm[8], ll[8];
    {
      int m = m0 + r, kk = k0 + g * 8;
      float xv[8] = {};
      if (m < BATCH && kk + 8 <= IN_DIM) {
        float4 x0 = *(const float4*)&xt[(size_t)m * IN_DIM + kk];
        float4 x1 = *(const float4*)&xt[(size_t)m * IN_DIM + kk + 4];
        xv[0] = x0.x; xv[1] = x0.y; xv[2] = x0.z; xv[3] = x0.w;
        xv[4] = x1.x; xv[5] = x1.y; xv[6] = x1.z; xv[7] = x1.w;
      }
#pragma unroll
      for (int q = 0; q < 8; q++) split3(xv[q], hh[q], mm[q], ll[q]);
    }
    size_t gb0 = (size_t)(n0 + r) * KPAD + k0 + g * 8;
    size_t gb1 = gb0 + (size_t)64 * KPAD;
    uint4 b0 = *(const uint4*)&Wch[gb0];
    uint4 b1 = *(const uint4*)&Wcm[gb0];
    uint4 b2 = *(const uint4*)&Wcl[gb0];
    uint4 b3 = *(const uint4*)&Wch[gb1];
    uint4 b4 = *(const uint4*)&Wcm[gb1];
    uint4 b5 = *(const uint4*)&Wcl[gb1];
    __syncthreads();
    int la = r * 40 + g * 8;
    *(uint4*)&Ab[0 * 2560 + la] = pack8(hh);
    *(uint4*)&Ab[1 * 2560 + la] = pack8(mm);
    *(uint4*)&Ab[2 * 2560 + la] = pack8(ll);
    *(uint4*)&Bb[0 * 5120 + la] = b0; *(uint4*)&Bb[1 * 5120 + la] = b1; *(uint4*)&Bb[2 * 5120 + la] = b2;
    int lb = la + 2560;
    *(uint4*)&Bb[0 * 5120 + lb] = b3; *(uint4*)&Bb[1 * 5120 + lb] = b4; *(uint4*)&Bb[2 * 5120 + lb] = b5;
    __syncthreads();
    bf16x8 ah[2], am[2], al[2];
#pragma unroll
    for (int fm = 0; fm < 2; fm++) {
      int row = (wm * 32 + fm * 16 + lr) * 40 + lg * 8;
      ah[fm] = *(const bf16x8*)&Ab[0 * 2560 + row];
      am[fm] = *(const bf16x8*)&Ab[1 * 2560 + row];
      al[fm] = *(const bf16x8*)&Ab[2 * 2560 + row];
    }
#pragma unroll
    for (int fn = 0; fn < 4; fn++) {
      int rown = (wn * 64 + fn * 16 + lr) * 40 + lg * 8;
      bf16x8 bh = *(const bf16x8*)&Bb[0 * 5120 + rown];
      bf16x8 bm = *(const bf16x8*)&Bb[1 * 5120 + rown];
      bf16x8 bl = *(const bf16x8*)&Bb[2 * 5120 + rown];
#pragma unroll
      for (int fm = 0; fm < 2; fm++) {
        f32x4 c = acc[fm][fn];
        c = __builtin_amdgcn_mfma_f32_16x16x32_bf16(ah[fm], bh, c, 0, 0, 0);
        c = __builtin_amdgcn_mfma_f32_16x16x32_bf16(ah[fm], bm, c, 0, 0, 0);
        c = __builtin_amdgcn_mfma_f32_16x16x32_bf16(am[fm], bh, c, 0, 0, 0);
        c = __builtin_amdgcn_mfma_f32_16x16x32_bf16(ah[fm], bl, c, 0, 0, 0);
        c = __builtin_amdgcn_mfma_f32_16x16x32_bf16(al[fm], bh, c, 0, 0, 0);
        c = __builtin_amdgcn_mfma_f32_16x16x32_bf16(am[fm], bm, c, 0, 0, 0);
        acc[fm][fn] = c;
      }
    }
  }
#pragma unroll
  for (int fm = 0; fm < 2; fm++)
#pragma unroll
    for (int fn = 0; fn < 4; fn++) {
      int n = n0 + wn * 64 + fn * 16 + lr;
      if (n >= HD1) continue;
      int mb = m0 + wm * 32 + fm * 16 + lg * 4;
#pragma unroll
      for (int r4 = 0; r4 < 4; r4++) {
        int m = mb + r4;
        if (m < BATCH) partT[((size_t)m * HD1 + n) * NS1 + s] = acc[fm][fn][r4];
      }
    }
}

// ---------------------------------------------------------------------------
// gemm2f body: chunked-PT epi + GEMM2 + hebb1/Wc epilogue. 247 jobs.
// PT built per 32-b chunk in LDS (15KB) from partT[b][j][8] dense reads.
// ---------------------------------------------------------------------------
__device__ __forceinline__ void gemm2f_body(
    int job, const float* __restrict__ partT,
    const unsigned short* __restrict__ XBh, const unsigned short* __restrict__ XBm,
    const unsigned short* __restrict__ XBl,
    const float* __restrict__ mem_old, const float* __restrict__ spike_old,
    float* __restrict__ mem_new, float* __restrict__ spike_new,
    const float* __restrict__ b1, const float* __restrict__ eta1,
    const float* __restrict__ beta1, const float* __restrict__ W1,
    const float* __restrict__ alpha1, float* __restrict__ H,
    unsigned short* __restrict__ Wch, unsigned short* __restrict__ Wcm,
    unsigned short* __restrict__ Wcl,
    unsigned short* PT, unsigned short* Bb, int tid) {
  int m0 = (job / 19) * 64, n0 = (job % 19) * 128;
  bool writer = (job % 19) == 0;
  int jl = tid & 63, bg = tid >> 6;
  int jj = m0 + jl;
  bool jok = (jj < HD1);
  float b1j = jok ? b1[jj] : 0.f;
  float e1j = jok ? eta1[jj] : 0.f;
  int r = tid >> 2, g = tid & 3;
  int w = tid >> 6, lane = tid & 63;
  int wm = w >> 1, wn = w & 1, lr = lane & 15, lg = lane >> 4;
  f32x4 acc[2][4] = {};
  for (int it = 0; it < 7; ++it) {
    int k0 = it * 32;
    // PT chunk: thread owns (jl, b = k0+bg*8+q)
    unsigned short ph[8], pmm[8], pll[8];
#pragma unroll
    for (int q = 0; q < 8; ++q) {
      int b = k0 + bg * 8 + q;
      float po = 0.f;
      if (b < BATCH && jok) {
        const float* pp = &partT[((size_t)b * HD1 + jj) * NS1];
        float ss = pp[0];
        ss += pp[1]; ss += pp[2]; ss += pp[3];
        ss += pp[4]; ss += pp[5]; ss += pp[6]; ss += pp[7];
        float st = ss + b1j;
        size_t ix = (size_t)b * HD1 + jj;
        float mo = mem_old[ix], so = spike_old[ix];
        float mnv = mo * (1.f - so) * 0.25f + st;
        if (writer) { mem_new[ix] = mnv; spike_new[ix] = (mnv - 0.4f > 0.f) ? 1.f : 0.f; }
        po = mnv * 2.5f - e1j;
      }
      split3(po, ph[q], pmm[q], pll[q]);
    }
    size_t gb0 = (size_t)(n0 + r) * BPAD + k0 + g * 8;
    size_t gb1 = gb0 + (size_t)64 * BPAD;
    uint4 b0 = *(const uint4*)&XBh[gb0];
    uint4 b1v = *(const uint4*)&XBm[gb0];
    uint4 b2 = *(const uint4*)&XBl[gb0];
    uint4 b3 = *(const uint4*)&XBh[gb1];
    uint4 b4 = *(const uint4*)&XBm[gb1];
    uint4 b5 = *(const uint4*)&XBl[gb1];
    __syncthreads();
    *(uint4*)&PT[0 * 2560 + jl * 40 + bg * 8] = pack8(ph);
    *(uint4*)&PT[1 * 2560 + jl * 40 + bg * 8] = pack8(pmm);
    *(uint4*)&PT[2 * 2560 + jl * 40 + bg * 8] = pack8(pll);
    int la = r * 40 + g * 8;
    *(uint4*)&Bb[0 * 5120 + la] = b0; *(uint4*)&Bb[1 * 5120 + la] = b1v; *(uint4*)&Bb[2 * 5120 + la] = b2;
    int lb = la + 2560;
    *(uint4*)&Bb[0 * 5120 + lb] = b3; *(uint4*)&Bb[1 * 5120 + lb] = b4; *(uint4*)&Bb[2 * 5120 + lb] = b5;
    __syncthreads();
    bf16x8 ah[2], am[2], al[2];
#pragma unroll
    for (int fm = 0; fm < 2; fm++) {
      int row = (wm * 32 + fm * 16 + lr) * 40 + lg * 8;
      ah[fm] = *(const bf16x8*)&PT[0 * 2560 + row];
      am[fm] = *(const bf16x8*)&PT[1 * 2560 + row];
      al[fm] = *(const bf16x8*)&PT[2 * 2560 + row];
    }
#pragma unroll
    for (int fn = 0; fn < 4; fn++) {
      int rown = (wn * 64 + fn * 16 + lr) * 40 + lg * 8;
      bf16x8 bh = *(const bf16x8*)&Bb[0 * 5120 + rown];
      bf16x8 bm = *(const bf16x8*)&Bb[1 * 5120 + rown];
      bf16x8 bl = *(const bf16x8*)&Bb[2 * 5120 + rown];
#pragma unroll
      for (int fm = 0; fm < 2; fm++) {
        f32x4 c = acc[fm][fn];
        c = __builtin_amdgcn_mfma_f32_16x16x32_bf16(ah[fm], bh, c, 0, 0, 0);
        c = __builtin_amdgcn_mfma_f32_16x16x32_bf16(ah[fm], bm, c, 0, 0, 0);
        c = __builtin_amdgcn_mfma_f32_16x16x32_bf16(am[fm], bh, c, 0, 0, 0);
        c = __builtin_amdgcn_mfma_f32_16x16x32_bf16(ah[fm], bl, c, 0, 0, 0);
        c = __builtin_amdgcn_mfma_f32_16x16x32_bf16(al[fm], bh, c, 0, 0, 0);
        c = __builtin_amdgcn_mfma_f32_16x16x32_bf16(am[fm], bm, c, 0, 0, 0);
        acc[fm][fn] = c;
      }
    }
  }
  float al1 = alpha1[0];
#pragma unroll
  for (int fm = 0; fm < 2; fm++)
#pragma unroll
    for (int fn = 0; fn < 4; fn++) {
      int i = n0 + wn * 64 + fn * 16 + lr;
      if (i >= IN_DIM) continue;
      float bc = fmaxf(beta1[i], 0.f);
      int jb = m0 + wm * 32 + fm * 16 + lg * 4;
#pragma unroll
      for (int r4 = 0; r4 < 4; r4++) {
        int j = jb + r4;
        if (j >= HD1) continue;
        size_t hx = (size_t)j * IN_DIM + i;
        float h = 0.99f * H[hx] - bc * acc[fm][fn][r4] * (1.f / 200.f);
        h = fminf(fmaxf(h, -5.f), 5.f);
        H[hx] = h;
        unsigned short vh, vm, vl;
        split3(W1[hx] + al1 * h, vh, vm, vl);
        size_t wx = (size_t)j * KPAD + i;
        Wch[wx] = vh; Wcm[wx] = vm; Wcl[wx] = vl;
      }
    }
}

// ---------------------------------------------------------------------------
// l2h2 column body: one block per output column j. Phase 1: wcomb to LDS,
// wave-parallel 200 dots (K=800) -> post2 in LDS + mem2/spike2/outs writes.
// Phase 2: thread-per-i hebb2 column update.
// ---------------------------------------------------------------------------
__device__ __forceinline__ void l2h2_col(
    int j, const float* __restrict__ s1, const float* __restrict__ W2,
    const float* __restrict__ b2, const float* __restrict__ alpha2,
    const float* __restrict__ beta2, const float* __restrict__ eta2,
    const float* __restrict__ mem2_old, const float* __restrict__ spike2_old,
    float* __restrict__ mem2_new, float* __restrict__ spike2_new,
    const float* __restrict__ h2_old, float* __restrict__ h2_new,
    float* __restrict__ outs, float* __restrict__ hebb2out, int is_last) {
  __shared__ float wcomb[HD1];
  __shared__ float post2s[BATCH];
  int tid = threadIdx.x;
  float a2 = alpha2[0];
  for (int i = tid; i < HD1; i += 256)
    wcomb[i] = W2[(size_t)j * HD1 + i] + a2 * h2_old[i * HD2 + j];
  __syncthreads();
  int wv = tid >> 6, lane = tid & 63;
  float b2j = b2[j], e2j = eta2[j];
  for (int b = wv * 50; b < wv * 50 + 50; ++b) {
    float acc = 0.f;
#pragma unroll
    for (int q = 0; q < 13; ++q) {
      int i = lane + q * 64;
      if (i < HD1) acc += s1[(size_t)b * HD1 + i] * wcomb[i];
    }
#pragma unroll
    for (int off = 32; off > 0; off >>= 1) acc += __shfl_down(acc, off, 64);
    if (lane == 0) {
      int ix = b * HD2 + j;
      float mo = mem2_old[ix], so = spike2_old[ix];
      float mnv = mo * (1.f - so) * 0.25f + (acc + b2j);
      mem2_new[ix]   = mnv;
      spike2_new[ix] = (mnv - 0.4f > 0.f) ? 1.f : 0.f;
      post2s[b] = mnv * 2.5f - e2j;
      outs[ix]  = mnv * 2.5f;
    }
  }
  __syncthreads();
  for (int i = tid; i < HD1; i += 256) {
    float acc = 0.f;
    for (int b = 0; b < BATCH; ++b)
      acc += s1[(size_t)b * HD1 + i] * post2s[b];
    float bc = fmaxf(beta2[i], 0.f);
    float h = 0.99f * h2_old[i * HD2 + j] - bc * acc * (1.f / 200.f);
    h = fminf(fmaxf(h, -5.f), 5.f);
    h2_new[i * HD2 + j] = h;
    if (is_last) hebb2out[i * HD2 + j] = h;
  }
}

// ---------------------------------------------------------------------------
// k_A: gemm1(t) [224 blocks] || l2h2(t-1) [10 blocks, if do_l2]
// ---------------------------------------------------------------------------
__global__ __launch_bounds__(256) void k_A(
    const float* __restrict__ xt, const unsigned short* __restrict__ Wch,
    const unsigned short* __restrict__ Wcm, const unsigned short* __restrict__ Wcl,
    float* __restrict__ partT, int do_l2,
    const float* __restrict__ s1, const float* __restrict__ W2,
    const float* __restrict__ b2, const float* __restrict__ alpha2,
    const float* __restrict__ beta2, const float* __restrict__ eta2,
    const float* __restrict__ mem2_old, const float* __restrict__ spike2_old,
    float* __restrict__ mem2_new, float* __restrict__ spike2_new,
    const float* __restrict__ h2_old, float* __restrict__ h2_new,
    float* __restrict__ outs) {
  __shared__ __align__(16) unsigned short Ab[3 * 2560];
  __shared__ __align__(16) unsigned short Bb[3 * 5120];
  int bid = blockIdx.x, tid = threadIdx.x;
  if (bid < 224) {
    gemm1_body(bid, xt, Wch, Wcm, Wcl, partT, Ab, Bb, tid);
  } else if (do_l2) {
    l2h2_col(bid - 224, s1, W2, b2, alpha2, beta2, eta2, mem2_old, spike2_old,
             mem2_new, spike2_new, h2_old, h2_new, outs, nullptr, 0);
  }
}

// ---------------------------------------------------------------------------
// k_B: gemm2f(t) [247 blocks] || x-split(t+1) into other XB buffer [256 blocks]
// ---------------------------------------------------------------------------
__global__ __launch_bounds__(256) void k_B(
    const float* __restrict__ partT, const unsigned short* __restrict__ XBh,
    const unsigned short* __restrict__ XBm, const unsigned short* __restrict__ XBl,
    const float* __restrict__ mem_old, const float* __restrict__ spike_old,
    float* __restrict__ mem_new, float* __restrict__ spike_new,
    const float* __restrict__ b1, const float* __restrict__ eta1,
    const float* __restrict__ beta1, const float* __restrict__ W1,
    const float* __restrict__ alpha1, float* __restrict__ H,
    unsigned short* __restrict__ Wch, unsigned short* __restrict__ Wcm,
    unsigned short* __restrict__ Wcl, int has_next,
    const float* __restrict__ xt_next, unsigned short* __restrict__ XB2h,
    unsigned short* __restrict__ XB2m, unsigned short* __restrict__ XB2l) {
  __shared__ __align__(16) unsigned short PT[3 * 2560];
  __shared__ __align__(16) unsigned short Bb[3 * 5120];
  int bid = blockIdx.x, tid = threadIdx.x;
  if (bid < 247) {
    gemm2f_body(bid, partT, XBh, XBm, XBl, mem_old, spike_old, mem_new, spike_new,
                b1, eta1, beta1, W1, alpha1, H, Wch, Wcm, Wcl, PT, Bb, tid);
  } else if (has_next) {
    int j0 = bid - 247;
    xb_tile(xt_next, j0, XB2h, XB2m, XB2l, PT, tid);
    if (j0 + 256 < 511) xb_tile(xt_next, j0 + 256, XB2h, XB2m, XB2l, PT, tid);
  }
}

// ---------------------------------------------------------------------------
// k_FIN: l2h2(7) [10 blocks] || hebb1out = H^T [481 blocks]
// ---------------------------------------------------------------------------
__global__ __launch_bounds__(256) void k_FIN(
    const float* __restrict__ s1, const float* __restrict__ W2,
    const float* __restrict__ b2, const float* __restrict__ alpha2,
    const float* __restrict__ beta2, const float* __restrict__ eta2,
    const float* __restrict__ mem2_old, const float* __restrict__ spike2_old,
    float* __restrict__ mem2_new, float* __restrict__ spike2_new,
    const float* __restrict__ h2_old, float* __restrict__ h2_new,
    float* __restrict__ outs, float* __restrict__ hebb2out,
    const float* __restrict__ H, float* __restrict__ hebb1out) {
  __shared__ float smf[64 * 65];
  int bid = blockIdx.x, tid = threadIdx.x;
  if (bid < 10) {
    l2h2_col(bid, s1, W2, b2, alpha2, beta2, eta2, mem2_old, spike2_old,
             mem2_new, spike2_new, h2_old, h2_new, outs, hebb2out, 1);
  } else {
    int job = bid - 10;
    int r0 = (job / 37) * 64, c0 = (job % 37) * 64;
#pragma unroll
    for (int q = 0; q < 16; q++) {
      int idx = q * 256 + tid;
      int r = idx >> 6, c = idx & 63;
      float v = (r0 + r < HD1 && c0 + c < IN_DIM) ? H[(size_t)(r0 + r) * IN_DIM + c0 + c] : 0.f;
      smf[r * 65 + c] = v;
    }
    __syncthreads();
#pragma unroll
    for (int q = 0; q < 16; q++) {
      int idx = q * 256 + tid;
      int r = idx >> 6, c = idx & 63;
      if (c0 + r < IN_DIM && r0 + c < HD1)
        hebb1out[(size_t)(c0 + r) * HD1 + r0 + c] = smf[c * 65 + r];
    }
  }
}

// ---------------------------------------------------------------------------
extern "C" void kernel_launch(void* const* d_in, const int* in_sizes, int n_in,
                              void* d_out, int out_size, void* d_ws, size_t ws_size,
                              hipStream_t stream) {
  const float* input    = (const float*)d_in[0];
  const float* hebb1_in = (const float*)d_in[1];
  const float* hebb2_in = (const float*)d_in[2];
  const float* W1       = (const float*)d_in[3];
  const float* b1       = (const float*)d_in[4];
  const float* W2       = (const float*)d_in[5];
  const float* b2       = (const float*)d_in[6];
  const float* alpha1   = (const float*)d_in[7];
  const float* alpha2   = (const float*)d_in[8];
  const float* beta1    = (const float*)d_in[9];
  const float* beta2    = (const float*)d_in[10];
  const float* eta1     = (const float*)d_in[11];
  const float* eta2     = (const float*)d_in[12];

  float* out      = (float*)d_out;
  float* outs     = out;
  float* hebb1out = out + BATCH * HD2;
  float* hebb2out = hebb1out + (size_t)IN_DIM * HD1;

  // ws: XB double-buffer (2x3 planes), Wc (3 planes), then fp32 area
  unsigned short* us = (unsigned short*)d_ws;
  unsigned short* XB0h = us;
  unsigned short* XB0m = XB0h + PLB;
  unsigned short* XB0l = XB0m + PLB;
  unsigned short* XB1h = XB0l + PLB;
  unsigned short* XB1m = XB1h + PLB;
  unsigned short* XB1l = XB1m + PLB;
  unsigned short* Wch  = XB1l + PLB;
  unsigned short* Wcm  = Wch + NK;
  unsigned short* Wcl  = Wcm + NK;
  size_t us_total = 6 * PLB + 3 * NK;   // 9,547,776

  float* fp = (float*)(us + us_total);
  float* partT   = fp;                                   // 200*800*8
  float* H       = partT + (size_t)BATCH * HD1 * NS1;    // 800*2312
  float* mem1a   = H + (size_t)HD1 * IN_DIM;
  float* mem1b   = mem1a + BATCH * HD1;
  float* spike1a = mem1b + BATCH * HD1;
  float* spike1b = spike1a + BATCH * HD1;
  float* mem2a   = spike1b + BATCH * HD1;
  float* mem2b   = mem2a + BATCH * HD2;
  float* spike2a = mem2b + BATCH * HD2;
  float* spike2b = spike2a + BATCH * HD2;
  float* h2a     = spike2b + BATCH * HD2;
  float* h2b     = h2a + HD1 * HD2;
  float* xall    = h2b + HD1 * HD2;                      // 8*200*2312

  float* mem1p[2]   = {mem1a, mem1b};
  float* spike1p[2] = {spike1a, spike1b};
  float* mem2p[2]   = {mem2a, mem2b};
  float* spike2p[2] = {spike2a, spike2b};
  float* h2p[2]     = {h2a, h2b};
  unsigned short* XBp[2][3] = {{XB0h, XB0m, XB0l}, {XB1h, XB1m, XB1l}};

  size_t sliceB = (size_t)BATCH * IN_DIM;

  k_pre<<<256, 256, 0, stream>>>(input, hebb1_in, hebb2_in, (uint4*)us, xall, H,
                                 mem1a, spike1a, mem2a, spike2a, h2a);
  k_pre2<<<256, 256, 0, stream>>>(W1, H, alpha1, xall, Wch, Wcm, Wcl,
                                  XB0h, XB0m, XB0l);

  for (int t = 0; t < TWIN; t++) {
    int o = t & 1, n = o ^ 1;
    // A(t): gemm1(t) || l2h2(t-1)
    //   l2h2(t-1): s1 = spike1p[t&1] (written by gemm2f(t-1)); mem2/h2 ping n->o
    k_A<<<234, 256, 0, stream>>>(xall + (size_t)t * sliceB, Wch, Wcm, Wcl, partT,
                                 (t > 0) ? 1 : 0, spike1p[o], W2, b2, alpha2,
                                 beta2, eta2, mem2p[n], spike2p[n], mem2p[o],
                                 spike2p[o], h2p[n], h2p[o], outs);
    // B(t): gemm2f(t) reads XB[o]; x-split(t+1) writes XB[n]
    k_B<<<503, 256, 0, stream>>>(partT, XBp[o][0], XBp[o][1], XBp[o][2],
                                 mem1p[o], spike1p[o], mem1p[n], spike1p[n],
                                 b1, eta1, beta1, W1, alpha1, H, Wch, Wcm, Wcl,
                                 (t < TWIN - 1) ? 1 : 0,
                                 xall + (size_t)(t + 1) * sliceB,
                                 XBp[n][0], XBp[n][1], XBp[n][2]);
  }
  // FIN: l2h2(7) (s1 = spike1p[0], mem2/h2 ping [1]->[0]) || H^T
  k_FIN<<<491, 256, 0, stream>>>(spike1p[0], W2, b2, alpha2, beta2, eta2,
                                 mem2p[1], spike2p[1], mem2p[0], spike2p[0],
                                 h2p[1], h2p[0], outs, hebb2out, H, hebb1out);
}